// Round 4
// baseline (3261.793 us; speedup 1.0000x reference)
//
#include <hip/hip_runtime.h>
#include <hip/hip_bf16.h>

#define NN 50000     // nodes per side (users == items == 50000)
#define NE 600000    // edges per relation
#define HF 256       // hidden features

typedef float f32x4 __attribute__((ext_vector_type(4)));
typedef _Float16 f16x8 __attribute__((ext_vector_type(8)));
typedef _Float16 f16x4 __attribute__((ext_vector_type(4)));

// order-preserving float<->uint encoding for atomicMax
__device__ __forceinline__ unsigned fenc(float f) {
  unsigned b = __float_as_uint(f);
  return (b & 0x80000000u) ? ~b : (b | 0x80000000u);
}
__device__ __forceinline__ float fdec(unsigned u) {
  return __uint_as_float((u & 0x80000000u) ? (u ^ 0x80000000u) : ~u);
}

// ---------- fp32 -> fp16 convert ----------
__global__ __launch_bounds__(256) void k_tofp16(const float* __restrict__ X,
                                                _Float16* __restrict__ Y, int n4) {
  int i = blockIdx.x * 256 + threadIdx.x;
  if (i < n4) {
    float4 v = reinterpret_cast<const float4*>(X)[i];
    f16x4 o = {(_Float16)v.x, (_Float16)v.y, (_Float16)v.z, (_Float16)v.w};
    reinterpret_cast<f16x4*>(Y)[i] = o;
  }
}

// ---------- W[K][256] (fp32) -> Wt[256][K] (fp16) ----------
__global__ __launch_bounds__(256) void k_transpose(const float* __restrict__ W,
                                                   _Float16* __restrict__ Wt, int K) {
  int idx = blockIdx.x * 256 + threadIdx.x;
  if (idx >= K * 256) return;
  int k = idx >> 8;
  int n = idx & 255;
  Wt[(size_t)n * K + k] = (_Float16)W[idx];
}

// ---------- attn projections: out[combo][k][h] = sum_d W[combo>>1][k, h*64+d] * a[h*64+d] ----------
__global__ __launch_bounds__(256) void k_makeattn(const float* __restrict__ Wfull,  // [2,K,256]
                                                  const float* __restrict__ al,    // [2,256]
                                                  const float* __restrict__ ar,    // [2,256]
                                                  int K, float* __restrict__ out) {
  int idx = blockIdx.x * 256 + threadIdx.x;
  if (idx >= 4 * K * 4) return;
  int h = idx & 3;
  int k = (idx >> 2) % K;
  int combo = idx / (4 * K);
  const float* W = Wfull + (size_t)(combo >> 1) * K * 256;
  const float* a = ((combo & 1) ? ar : al) + (combo >> 1) * 256 + h * 64;
  const float* wrow = W + (size_t)k * 256 + h * 64;
  float s = 0.f;
#pragma unroll 8
  for (int d = 0; d < 64; ++d) s += wrow[d] * a[d];
  out[(size_t)combo * K * 4 + k * 4 + h] = s;
}

// ---------- dual GEMV (X fp16): one wave per row ----------
__global__ __launch_bounds__(256) void k_gemv4(const _Float16* __restrict__ X,
                                               const float* __restrict__ wa,  // [K][4]
                                               const float* __restrict__ wb,  // [K][4]
                                               float* __restrict__ outA, float* __restrict__ outB,
                                               int K) {
  int wid = (blockIdx.x * 256 + threadIdx.x) >> 6;
  if (wid >= NN) return;
  int lane = threadIdx.x & 63;
  float pa0 = 0.f, pa1 = 0.f, pa2 = 0.f, pa3 = 0.f;
  float pb0 = 0.f, pb1 = 0.f, pb2 = 0.f, pb3 = 0.f;
  int k0 = lane * 4;
  if (k0 < K) {
    f16x4 x = *reinterpret_cast<const f16x4*>(X + (size_t)wid * K + k0);
    float xv[4] = {(float)x.x, (float)x.y, (float)x.z, (float)x.w};
#pragma unroll
    for (int j = 0; j < 4; ++j) {
      float4 wav = *reinterpret_cast<const float4*>(wa + (k0 + j) * 4);
      float4 wbv = *reinterpret_cast<const float4*>(wb + (k0 + j) * 4);
      pa0 += xv[j] * wav.x; pa1 += xv[j] * wav.y; pa2 += xv[j] * wav.z; pa3 += xv[j] * wav.w;
      pb0 += xv[j] * wbv.x; pb1 += xv[j] * wbv.y; pb2 += xv[j] * wbv.z; pb3 += xv[j] * wbv.w;
    }
  }
#pragma unroll
  for (int off = 32; off > 0; off >>= 1) {
    pa0 += __shfl_down(pa0, off); pa1 += __shfl_down(pa1, off);
    pa2 += __shfl_down(pa2, off); pa3 += __shfl_down(pa3, off);
    pb0 += __shfl_down(pb0, off); pb1 += __shfl_down(pb1, off);
    pb2 += __shfl_down(pb2, off); pb3 += __shfl_down(pb3, off);
  }
  if (lane == 0) {
    *reinterpret_cast<float4*>(outA + (size_t)wid * 4) = (float4){pa0, pa1, pa2, pa3};
    *reinterpret_cast<float4*>(outB + (size_t)wid * 4) = (float4){pb0, pb1, pb2, pb3};
  }
}

// ---------- GEMM: Z[M,256](fp16) = A[M,K](fp16) @ W[K,256] ----------
__global__ __launch_bounds__(256) void k_gemm(const _Float16* __restrict__ A,
                                              const _Float16* __restrict__ Wt,
                                              _Float16* __restrict__ Z,
                                              int M, int K) {
  int wave = threadIdx.x >> 6;
  int lane = threadIdx.x & 63;
  int lr = lane & 15;   // fragment row (A) / col (B)
  int kg = lane >> 4;   // k-group: k = kg*8 + j
  int row0 = blockIdx.x * 64;
  int col0 = wave * 64;
  f32x4 acc[4][4];
#pragma unroll
  for (int i = 0; i < 4; ++i)
#pragma unroll
    for (int j = 0; j < 4; ++j) acc[i][j] = (f32x4){0.f, 0.f, 0.f, 0.f};

  for (int k0 = 0; k0 < K; k0 += 32) {
    f16x8 af[4], bfr[4];
#pragma unroll
    for (int mt = 0; mt < 4; ++mt) {
      int r = row0 + mt * 16 + lr;
      if (r >= M) r = M - 1;  // clamp loads; stores are guarded
      af[mt] = *reinterpret_cast<const f16x8*>(A + (size_t)r * K + k0 + kg * 8);
    }
#pragma unroll
    for (int ct = 0; ct < 4; ++ct) {
      int c = col0 + ct * 16 + lr;
      bfr[ct] = *reinterpret_cast<const f16x8*>(Wt + (size_t)c * K + k0 + kg * 8);
    }
#pragma unroll
    for (int mt = 0; mt < 4; ++mt)
#pragma unroll
      for (int ct = 0; ct < 4; ++ct)
        acc[mt][ct] = __builtin_amdgcn_mfma_f32_16x16x32_f16(af[mt], bfr[ct], acc[mt][ct], 0, 0, 0);
  }
  // C/D layout: col = lane&15, row = (lane>>4)*4 + reg
#pragma unroll
  for (int mt = 0; mt < 4; ++mt) {
#pragma unroll
    for (int r = 0; r < 4; ++r) {
      int row = row0 + mt * 16 + kg * 4 + r;
      if (row < M) {
#pragma unroll
        for (int ct = 0; ct < 4; ++ct) {
          int col = col0 + ct * 16 + lr;
          Z[(size_t)row * HF + col] = (_Float16)acc[mt][ct][r];
        }
      }
    }
  }
}

// ---------- CSR build ----------
__global__ __launch_bounds__(256) void k_hist(const int* __restrict__ dst, int* __restrict__ counts) {
  int e = blockIdx.x * 256 + threadIdx.x;
  if (e < NE) atomicAdd(&counts[dst[e]], 1);
}

__global__ __launch_bounds__(1024) void k_scan1(const int* __restrict__ counts,
                                                int* __restrict__ rp, int* __restrict__ bsum) {
  __shared__ int tmp[1024];
  int i = blockIdx.x * 1024 + threadIdx.x;
  int v = (i < NN) ? counts[i] : 0;
  tmp[threadIdx.x] = v;
  __syncthreads();
  for (int off = 1; off < 1024; off <<= 1) {
    int t = (threadIdx.x >= off) ? tmp[threadIdx.x - off] : 0;
    __syncthreads();
    tmp[threadIdx.x] += t;
    __syncthreads();
  }
  if (i < NN) rp[i] = tmp[threadIdx.x] - v;  // block-local exclusive
  if (threadIdx.x == 1023) bsum[blockIdx.x] = tmp[1023];
}

__global__ __launch_bounds__(64) void k_scan2(int* __restrict__ bsum, int nb) {
  int l = threadIdx.x;
  int orig = (l < nb) ? bsum[l] : 0;
  int v = orig;
#pragma unroll
  for (int off = 1; off < 64; off <<= 1) {
    int t = __shfl_up(v, off);
    if (l >= off) v += t;
  }
  if (l < nb) bsum[l] = v - orig;  // exclusive
}

__global__ __launch_bounds__(1024) void k_scan3(int* __restrict__ rp, const int* __restrict__ bsum) {
  int i = blockIdx.x * 1024 + threadIdx.x;
  if (i < NN) rp[i] += bsum[blockIdx.x];
  if (i == 0) rp[NN] = NE;
}

__global__ __launch_bounds__(256) void k_scatter(const int* __restrict__ src, const int* __restrict__ dst,
                                                 const int* __restrict__ rp, int* __restrict__ fill,
                                                 int* __restrict__ csrc, int* __restrict__ epos) {
  int e = blockIdx.x * 256 + threadIdx.x;
  if (e < NE) {
    int d = dst[e];
    int pos = rp[d] + atomicAdd(&fill[d], 1);
    csrc[pos] = src[e];
    epos[e] = pos;
  }
}

// ---------- edge-parallel softmax prep ----------
__global__ __launch_bounds__(256) void k_edgelogit(const int* __restrict__ src, const int* __restrict__ dst,
                                                   const float* __restrict__ el, const float* __restrict__ er,
                                                   float* __restrict__ xval, unsigned* __restrict__ menc) {
  int e = blockIdx.x * 256 + threadIdx.x;
  if (e >= NE) return;
  int s = src[e], d = dst[e];
  float4 a = reinterpret_cast<const float4*>(el)[s];
  float4 b = reinterpret_cast<const float4*>(er)[d];
  float4 x;
  x.x = a.x + b.x; x.x = x.x >= 0.f ? x.x : 0.2f * x.x;
  x.y = a.y + b.y; x.y = x.y >= 0.f ? x.y : 0.2f * x.y;
  x.z = a.z + b.z; x.z = x.z >= 0.f ? x.z : 0.2f * x.z;
  x.w = a.w + b.w; x.w = x.w >= 0.f ? x.w : 0.2f * x.w;
  reinterpret_cast<float4*>(xval)[e] = x;
  atomicMax(&menc[d * 4 + 0], fenc(x.x));
  atomicMax(&menc[d * 4 + 1], fenc(x.y));
  atomicMax(&menc[d * 4 + 2], fenc(x.z));
  atomicMax(&menc[d * 4 + 3], fenc(x.w));
}

__global__ __launch_bounds__(256) void k_edgeweight(const float* __restrict__ xval,
                                                    const int* __restrict__ dst,
                                                    const unsigned* __restrict__ menc,
                                                    float* __restrict__ ssum,
                                                    const int* __restrict__ epos,
                                                    float* __restrict__ wbuf) {
  int e = blockIdx.x * 256 + threadIdx.x;
  if (e >= NE) return;
  float4 x = reinterpret_cast<const float4*>(xval)[e];
  int d = dst[e];
  uint4 mu = reinterpret_cast<const uint4*>(menc)[d];
  float4 ex;
  ex.x = __expf(x.x - fdec(mu.x));
  ex.y = __expf(x.y - fdec(mu.y));
  ex.z = __expf(x.z - fdec(mu.z));
  ex.w = __expf(x.w - fdec(mu.w));
  atomicAdd(&ssum[d * 4 + 0], ex.x);
  atomicAdd(&ssum[d * 4 + 1], ex.y);
  atomicAdd(&ssum[d * 4 + 2], ex.z);
  atomicAdd(&ssum[d * 4 + 3], ex.w);
  reinterpret_cast<float4*>(wbuf)[epos[e]] = ex;
}

// ---------- single-pass aggregation: wave per dst, 2 edges in flight per iter ----------
__global__ __launch_bounds__(256) void k_aggregate_sp(
    const int* __restrict__ rp, const int* __restrict__ csrc,
    const float* __restrict__ wbuf, const float* __restrict__ ssum,
    const _Float16* __restrict__ Z, const float* __restrict__ bias,
    float* __restrict__ out) {
  int wid = (blockIdx.x * 256 + threadIdx.x) >> 6;
  if (wid >= NN) return;
  int lane = threadIdx.x & 63;
  int half = lane >> 5, l5 = lane & 31;
  int c0 = l5 * 8;
  int h = l5 >> 3;
  int beg = rp[wid], end = rp[wid + 1];
  float invh = (end > beg) ? 1.0f / ssum[wid * 4 + h] : 0.f;
  float a[8] = {0.f, 0.f, 0.f, 0.f, 0.f, 0.f, 0.f, 0.f};
  int pos = beg + half;
  // 2x manual unroll (per half) -> up to 4 Z-rows in flight per wave
  for (; pos + 2 < end; pos += 4) {
    int s0 = csrc[pos], s1 = csrc[pos + 2];
    float w0 = wbuf[pos * 4 + h], w1 = wbuf[(pos + 2) * 4 + h];
    f16x8 z0 = *reinterpret_cast<const f16x8*>(Z + (size_t)s0 * HF + c0);
    f16x8 z1 = *reinterpret_cast<const f16x8*>(Z + (size_t)s1 * HF + c0);
#pragma unroll
    for (int j = 0; j < 8; ++j) a[j] += w0 * (float)z0[j];
#pragma unroll
    for (int j = 0; j < 8; ++j) a[j] += w1 * (float)z1[j];
  }
  if (pos < end) {
    int s0 = csrc[pos];
    float w0 = wbuf[pos * 4 + h];
    f16x8 z0 = *reinterpret_cast<const f16x8*>(Z + (size_t)s0 * HF + c0);
#pragma unroll
    for (int j = 0; j < 8; ++j) a[j] += w0 * (float)z0[j];
  }
#pragma unroll
  for (int j = 0; j < 8; ++j) a[j] += __shfl_xor(a[j], 32);
  if (half == 0) {
    const float4* bp4 = reinterpret_cast<const float4*>(bias + c0);
    float4 b0 = bp4[0], b1 = bp4[1];
    float4 r0 = {a[0] * invh + b0.x, a[1] * invh + b0.y, a[2] * invh + b0.z, a[3] * invh + b0.w};
    float4 r1 = {a[4] * invh + b1.x, a[5] * invh + b1.y, a[6] * invh + b1.z, a[7] * invh + b1.w};
    float4* op = reinterpret_cast<float4*>(out + (size_t)wid * HF + c0);
    op[0] = r0;
    op[1] = r1;
  }
}

// ---------- batchnorm ----------
__global__ __launch_bounds__(256) void k_bn_stats(const float* __restrict__ X,
                                                  float* __restrict__ sums, float* __restrict__ sqs) {
  int c = threadIdx.x;
  float s = 0.f, q = 0.f;
  for (int r = blockIdx.x; r < NN; r += gridDim.x) {
    float v = X[(size_t)r * HF + c];
    s += v;
    q += v * v;
  }
  atomicAdd(&sums[c], s);
  atomicAdd(&sqs[c], q);
}

__global__ __launch_bounds__(256) void k_bn_apply(const float* __restrict__ X,
    const float* __restrict__ sums, const float* __restrict__ sqs,
    const float* __restrict__ g, const float* __restrict__ bt,
    _Float16* __restrict__ Y, int act) {
  int idx = blockIdx.x * 256 + threadIdx.x;  // grid = NN blocks
  int c = idx & 255;
  const float invN = 1.0f / NN;
  float mu = sums[c] * invN;
  float var = sqs[c] * invN - mu * mu;
  float sc = rsqrtf(var + 1e-5f) * g[c];
  float v = (X[idx] - mu) * sc + bt[c];
  v = act ? tanhf(v) : (v >= 0.f ? v : 0.01f * v);
  Y[idx] = (_Float16)v;
}

extern "C" void kernel_launch(void* const* d_in, const int* in_sizes, int n_in,
                              void* d_out, int out_size, void* d_ws, size_t ws_size,
                              hipStream_t stream) {
  (void)in_sizes; (void)n_in; (void)out_size; (void)ws_size;
  const float* x_user = (const float*)d_in[0];
  const float* x_item = (const float*)d_in[1];
  const int* ui_src = (const int*)d_in[2];
  const int* ui_dst = (const int*)d_in[3];
  const int* iu_src = (const int*)d_in[4];
  const int* iu_dst = (const int*)d_in[5];
  const float *Wp[4], *alp[4], *arp[4], *bp[4];
  for (int l = 0; l < 4; ++l) {
    Wp[l]  = (const float*)d_in[6 + 4 * l];
    alp[l] = (const float*)d_in[7 + 4 * l];
    arp[l] = (const float*)d_in[8 + 4 * l];
    bp[l]  = (const float*)d_in[9 + 4 * l];
  }
  const float* bng = (const float*)d_in[22];
  const float* bnb = (const float*)d_in[23];

  char* w = (char*)d_ws;
  auto alloc = [&](size_t bytes) -> void* {
    void* p = (void*)w;
    w += (bytes + 255) & ~(size_t)255;
    return p;
  };
  _Float16* XU16 = (_Float16*)alloc((size_t)NN * 128 * 2);
  _Float16* XI16 = (_Float16*)alloc((size_t)NN * 128 * 2);
  _Float16* H16U = (_Float16*)alloc((size_t)NN * HF * 2);
  _Float16* H16I = (_Float16*)alloc((size_t)NN * HF * 2);
  _Float16* Z = (_Float16*)alloc((size_t)NN * HF * 2);
  float* RAWU = (float*)alloc((size_t)NN * HF * 4);
  float* RAWI = (float*)alloc((size_t)NN * HF * 4);
  float* EL0 = (float*)alloc((size_t)NN * 4 * 4);
  float* ER0 = (float*)alloc((size_t)NN * 4 * 4);
  float* EL1 = (float*)alloc((size_t)NN * 4 * 4);
  float* ER1 = (float*)alloc((size_t)NN * 4 * 4);
  _Float16* WT = (_Float16*)alloc((size_t)8 * 65536 * 2);
  float* ATTN = (float*)alloc((size_t)4 * 256 * 4 * 4);
  int* rp_ui = (int*)alloc((size_t)(NN + 1) * 4);
  int* rp_iu = (int*)alloc((size_t)(NN + 1) * 4);
  int* csrc_ui = (int*)alloc((size_t)NE * 4);
  int* csrc_iu = (int*)alloc((size_t)NE * 4);
  int* epos_ui = (int*)alloc((size_t)NE * 4);
  int* epos_iu = (int*)alloc((size_t)NE * 4);
  float* xval = (float*)alloc((size_t)NE * 4 * 4);
  float* wbuf = (float*)alloc((size_t)NE * 4 * 4);
  unsigned* menc = (unsigned*)alloc((size_t)NN * 4 * 4 * 2);  // menc | ssum contiguous
  float* ssum = (float*)(menc + (size_t)NN * 4);
  int* counts = (int*)alloc((size_t)4 * NN * 4);  // counts_ui | counts_iu | fill_ui | fill_iu
  int* bsum_ui = (int*)alloc((size_t)64 * 4);
  int* bsum_iu = (int*)alloc((size_t)64 * 4);
  float* stats = (float*)alloc((size_t)6 * 512 * 4);

  int* counts_ui = counts;
  int* counts_iu = counts + NN;
  int* fill_ui = counts + 2 * NN;
  int* fill_iu = counts + 3 * NN;

  hipMemsetAsync(counts, 0, (size_t)4 * NN * 4, stream);
  hipMemsetAsync(stats, 0, (size_t)6 * 512 * 4, stream);

  // input conversion + weight transposes (once per call)
  k_tofp16<<<(NN * 128 / 4 + 255) / 256, 256, 0, stream>>>(x_user, XU16, NN * 128 / 4);
  k_tofp16<<<(NN * 128 / 4 + 255) / 256, 256, 0, stream>>>(x_item, XI16, NN * 128 / 4);
  for (int l = 0; l < 4; ++l) {
    int K = (l == 0) ? 128 : 256;
    for (int r = 0; r < 2; ++r)
      k_transpose<<<K, 256, 0, stream>>>(Wp[l] + (size_t)r * K * HF, WT + (size_t)(l * 2 + r) * 65536, K);
  }
  // CSR builds (edges shared by all layers)
  int egrid = (NE + 255) / 256;
  int nscan = (NN + 1023) / 1024;
  k_hist<<<egrid, 256, 0, stream>>>(ui_dst, counts_ui);
  k_hist<<<egrid, 256, 0, stream>>>(iu_dst, counts_iu);
  k_scan1<<<nscan, 1024, 0, stream>>>(counts_ui, rp_ui, bsum_ui);
  k_scan2<<<1, 64, 0, stream>>>(bsum_ui, nscan);
  k_scan3<<<nscan, 1024, 0, stream>>>(rp_ui, bsum_ui);
  k_scan1<<<nscan, 1024, 0, stream>>>(counts_iu, rp_iu, bsum_iu);
  k_scan2<<<1, 64, 0, stream>>>(bsum_iu, nscan);
  k_scan3<<<nscan, 1024, 0, stream>>>(rp_iu, bsum_iu);
  k_scatter<<<egrid, 256, 0, stream>>>(ui_src, ui_dst, rp_ui, fill_ui, csrc_ui, epos_ui);
  k_scatter<<<egrid, 256, 0, stream>>>(iu_src, iu_dst, rp_iu, fill_iu, csrc_iu, epos_iu);

  const _Float16* hu16 = XU16;
  const _Float16* hi16 = XI16;
  int mgrid = (NN + 63) / 64;
  int agrid = (NN + 3) / 4;
  float* out_user = (float*)d_out;
  float* out_item = (float*)d_out + (size_t)NN * HF;

  for (int l = 0; l < 4; ++l) {
    int K = (l == 0) ? 128 : 256;
    const _Float16* W0t = WT + (size_t)(l * 2 + 0) * 65536;
    const _Float16* W1t = WT + (size_t)(l * 2 + 1) * 65536;

    // attn projection tables: wal0 | war0 | wal1 | war1, each [K][4]
    k_makeattn<<<(4 * K * 4 + 255) / 256, 256, 0, stream>>>(Wp[l], alp[l], arp[l], K, ATTN);
    // hu -> el_ui (wal0), er_iu (war1); hi -> er_ui (war0), el_iu (wal1)
    k_gemv4<<<agrid, 256, 0, stream>>>(hu16, ATTN + 0 * K * 4, ATTN + 3 * K * 4, EL0, ER1, K);
    k_gemv4<<<agrid, 256, 0, stream>>>(hi16, ATTN + 1 * K * 4, ATTN + 2 * K * 4, ER0, EL1, K);

    // relation u->i (dst = items): z_src = hu@W0
    hipMemsetAsync(menc, 0, (size_t)NN * 4 * 4 * 2, stream);
    k_edgelogit<<<egrid, 256, 0, stream>>>(ui_src, ui_dst, EL0, ER0, xval, menc);
    k_edgeweight<<<egrid, 256, 0, stream>>>(xval, ui_dst, menc, ssum, epos_ui, wbuf);
    k_gemm<<<mgrid, 256, 0, stream>>>(hu16, W0t, Z, NN, K);
    k_aggregate_sp<<<agrid, 256, 0, stream>>>(rp_ui, csrc_ui, wbuf, ssum, Z, bp[l] + 0,
                                              (l < 3) ? RAWI : out_item);

    // relation i->u (dst = users): z_src = hi@W1
    hipMemsetAsync(menc, 0, (size_t)NN * 4 * 4 * 2, stream);
    k_edgelogit<<<egrid, 256, 0, stream>>>(iu_src, iu_dst, EL1, ER1, xval, menc);
    k_edgeweight<<<egrid, 256, 0, stream>>>(xval, iu_dst, menc, ssum, epos_iu, wbuf);
    k_gemm<<<mgrid, 256, 0, stream>>>(hi16, W1t, Z, NN, K);
    k_aggregate_sp<<<agrid, 256, 0, stream>>>(rp_iu, csrc_iu, wbuf, ssum, Z, bp[l] + 256,
                                              (l < 3) ? RAWU : out_user);

    if (l < 3) {
      int act = (l == 2) ? 1 : 0;
      float* su = stats + (size_t)(l * 2 + 0) * 512;
      float* qu = su + 256;
      float* si = stats + (size_t)(l * 2 + 1) * 512;
      float* qi = si + 256;
      k_bn_stats<<<512, 256, 0, stream>>>(RAWU, su, qu);
      k_bn_stats<<<512, 256, 0, stream>>>(RAWI, si, qi);
      k_bn_apply<<<NN, 256, 0, stream>>>(RAWU, su, qu, bng + (size_t)(l * 2 + 0) * 256,
                                         bnb + (size_t)(l * 2 + 0) * 256, H16U, act);
      k_bn_apply<<<NN, 256, 0, stream>>>(RAWI, si, qi, bng + (size_t)(l * 2 + 1) * 256,
                                         bnb + (size_t)(l * 2 + 1) * 256, H16I, act);
      hu16 = H16U;
      hi16 = H16I;
    }
  }
}

// Round 5
// 1503.472 us; speedup vs baseline: 2.1695x; 2.1695x over previous
//
#include <hip/hip_runtime.h>
#include <hip/hip_bf16.h>

#define NN 50000     // nodes per side (users == items == 50000)
#define NE 600000    // edges per relation
#define HF 256       // hidden features

typedef float f32x4 __attribute__((ext_vector_type(4)));
typedef _Float16 f16x8 __attribute__((ext_vector_type(8)));
typedef _Float16 f16x4 __attribute__((ext_vector_type(4)));

// ---------- fp32 -> fp16 convert ----------
__global__ __launch_bounds__(256) void k_tofp16(const float* __restrict__ X,
                                                _Float16* __restrict__ Y, int n4) {
  int i = blockIdx.x * 256 + threadIdx.x;
  if (i < n4) {
    float4 v = reinterpret_cast<const float4*>(X)[i];
    f16x4 o = {(_Float16)v.x, (_Float16)v.y, (_Float16)v.z, (_Float16)v.w};
    reinterpret_cast<f16x4*>(Y)[i] = o;
  }
}

// ---------- W[K][256] (fp32) -> Wt[256][K] (fp16) ----------
__global__ __launch_bounds__(256) void k_transpose(const float* __restrict__ W,
                                                   _Float16* __restrict__ Wt, int K) {
  int idx = blockIdx.x * 256 + threadIdx.x;
  if (idx >= K * 256) return;
  int k = idx >> 8;
  int n = idx & 255;
  Wt[(size_t)n * K + k] = (_Float16)W[idx];
}

// ---------- attn projections: out[combo][k][h] = sum_d W[combo>>1][k, h*64+d] * a[h*64+d] ----------
__global__ __launch_bounds__(256) void k_makeattn(const float* __restrict__ Wfull,  // [2,K,256]
                                                  const float* __restrict__ al,    // [2,256]
                                                  const float* __restrict__ ar,    // [2,256]
                                                  int K, float* __restrict__ out) {
  int idx = blockIdx.x * 256 + threadIdx.x;
  if (idx >= 4 * K * 4) return;
  int h = idx & 3;
  int k = (idx >> 2) % K;
  int combo = idx / (4 * K);
  const float* W = Wfull + (size_t)(combo >> 1) * K * 256;
  const float* a = ((combo & 1) ? ar : al) + (combo >> 1) * 256 + h * 64;
  const float* wrow = W + (size_t)k * 256 + h * 64;
  float s = 0.f;
#pragma unroll 8
  for (int d = 0; d < 64; ++d) s += wrow[d] * a[d];
  out[(size_t)combo * K * 4 + k * 4 + h] = s;
}

// ---------- dual GEMV (X fp16): one wave per row ----------
__global__ __launch_bounds__(256) void k_gemv4(const _Float16* __restrict__ X,
                                               const float* __restrict__ wa,  // [K][4]
                                               const float* __restrict__ wb,  // [K][4]
                                               float* __restrict__ outA, float* __restrict__ outB,
                                               int K) {
  int wid = (blockIdx.x * 256 + threadIdx.x) >> 6;
  if (wid >= NN) return;
  int lane = threadIdx.x & 63;
  float pa0 = 0.f, pa1 = 0.f, pa2 = 0.f, pa3 = 0.f;
  float pb0 = 0.f, pb1 = 0.f, pb2 = 0.f, pb3 = 0.f;
  int k0 = lane * 4;
  if (k0 < K) {
    f16x4 x = *reinterpret_cast<const f16x4*>(X + (size_t)wid * K + k0);
    float xv[4] = {(float)x.x, (float)x.y, (float)x.z, (float)x.w};
#pragma unroll
    for (int j = 0; j < 4; ++j) {
      float4 wav = *reinterpret_cast<const float4*>(wa + (k0 + j) * 4);
      float4 wbv = *reinterpret_cast<const float4*>(wb + (k0 + j) * 4);
      pa0 += xv[j] * wav.x; pa1 += xv[j] * wav.y; pa2 += xv[j] * wav.z; pa3 += xv[j] * wav.w;
      pb0 += xv[j] * wbv.x; pb1 += xv[j] * wbv.y; pb2 += xv[j] * wbv.z; pb3 += xv[j] * wbv.w;
    }
  }
#pragma unroll
  for (int off = 32; off > 0; off >>= 1) {
    pa0 += __shfl_down(pa0, off); pa1 += __shfl_down(pa1, off);
    pa2 += __shfl_down(pa2, off); pa3 += __shfl_down(pa3, off);
    pb0 += __shfl_down(pb0, off); pb1 += __shfl_down(pb1, off);
    pb2 += __shfl_down(pb2, off); pb3 += __shfl_down(pb3, off);
  }
  if (lane == 0) {
    *reinterpret_cast<float4*>(outA + (size_t)wid * 4) = (float4){pa0, pa1, pa2, pa3};
    *reinterpret_cast<float4*>(outB + (size_t)wid * 4) = (float4){pb0, pb1, pb2, pb3};
  }
}

// ---------- GEMM: Z[M,256](fp16) = A[M,K](fp16) @ W[K,256] ----------
__global__ __launch_bounds__(256) void k_gemm(const _Float16* __restrict__ A,
                                              const _Float16* __restrict__ Wt,
                                              _Float16* __restrict__ Z,
                                              int M, int K) {
  int wave = threadIdx.x >> 6;
  int lane = threadIdx.x & 63;
  int lr = lane & 15;   // fragment row (A) / col (B)
  int kg = lane >> 4;   // k-group: k = kg*8 + j
  int row0 = blockIdx.x * 64;
  int col0 = wave * 64;
  f32x4 acc[4][4];
#pragma unroll
  for (int i = 0; i < 4; ++i)
#pragma unroll
    for (int j = 0; j < 4; ++j) acc[i][j] = (f32x4){0.f, 0.f, 0.f, 0.f};

  for (int k0 = 0; k0 < K; k0 += 32) {
    f16x8 af[4], bfr[4];
#pragma unroll
    for (int mt = 0; mt < 4; ++mt) {
      int r = row0 + mt * 16 + lr;
      if (r >= M) r = M - 1;  // clamp loads; stores are guarded
      af[mt] = *reinterpret_cast<const f16x8*>(A + (size_t)r * K + k0 + kg * 8);
    }
#pragma unroll
    for (int ct = 0; ct < 4; ++ct) {
      int c = col0 + ct * 16 + lr;
      bfr[ct] = *reinterpret_cast<const f16x8*>(Wt + (size_t)c * K + k0 + kg * 8);
    }
#pragma unroll
    for (int mt = 0; mt < 4; ++mt)
#pragma unroll
      for (int ct = 0; ct < 4; ++ct)
        acc[mt][ct] = __builtin_amdgcn_mfma_f32_16x16x32_f16(af[mt], bfr[ct], acc[mt][ct], 0, 0, 0);
  }
  // C/D layout: col = lane&15, row = (lane>>4)*4 + reg
#pragma unroll
  for (int mt = 0; mt < 4; ++mt) {
#pragma unroll
    for (int r = 0; r < 4; ++r) {
      int row = row0 + mt * 16 + kg * 4 + r;
      if (row < M) {
#pragma unroll
        for (int ct = 0; ct < 4; ++ct) {
          int col = col0 + ct * 16 + lr;
          Z[(size_t)row * HF + col] = (_Float16)acc[mt][ct][r];
        }
      }
    }
  }
}

// ---------- CSR build ----------
__global__ __launch_bounds__(256) void k_hist(const int* __restrict__ dst, int* __restrict__ counts) {
  int e = blockIdx.x * 256 + threadIdx.x;
  if (e < NE) atomicAdd(&counts[dst[e]], 1);
}

__global__ __launch_bounds__(1024) void k_scan1(const int* __restrict__ counts,
                                                int* __restrict__ rp, int* __restrict__ bsum) {
  __shared__ int tmp[1024];
  int i = blockIdx.x * 1024 + threadIdx.x;
  int v = (i < NN) ? counts[i] : 0;
  tmp[threadIdx.x] = v;
  __syncthreads();
  for (int off = 1; off < 1024; off <<= 1) {
    int t = (threadIdx.x >= off) ? tmp[threadIdx.x - off] : 0;
    __syncthreads();
    tmp[threadIdx.x] += t;
    __syncthreads();
  }
  if (i < NN) rp[i] = tmp[threadIdx.x] - v;  // block-local exclusive
  if (threadIdx.x == 1023) bsum[blockIdx.x] = tmp[1023];
}

__global__ __launch_bounds__(64) void k_scan2(int* __restrict__ bsum, int nb) {
  int l = threadIdx.x;
  int orig = (l < nb) ? bsum[l] : 0;
  int v = orig;
#pragma unroll
  for (int off = 1; off < 64; off <<= 1) {
    int t = __shfl_up(v, off);
    if (l >= off) v += t;
  }
  if (l < nb) bsum[l] = v - orig;  // exclusive
}

__global__ __launch_bounds__(1024) void k_scan3(int* __restrict__ rp, const int* __restrict__ bsum) {
  int i = blockIdx.x * 1024 + threadIdx.x;
  if (i < NN) rp[i] += bsum[blockIdx.x];
  if (i == 0) rp[NN] = NE;
}

__global__ __launch_bounds__(256) void k_scatter(const int* __restrict__ src, const int* __restrict__ dst,
                                                 const int* __restrict__ rp, int* __restrict__ fill,
                                                 int* __restrict__ csrc) {
  int e = blockIdx.x * 256 + threadIdx.x;
  if (e < NE) {
    int d = dst[e];
    int pos = rp[d] + atomicAdd(&fill[d], 1);
    csrc[pos] = src[e];
  }
}

// ---------- fused GAT aggregation v3: wave per dst, lane-parallel softmax, 4-deep Z gathers ----------
__device__ __forceinline__ float pick_h(float4 v, int h) {
  float r = v.x;
  r = (h == 1) ? v.y : r;
  r = (h == 2) ? v.z : r;
  r = (h == 3) ? v.w : r;
  return r;
}

__global__ __launch_bounds__(256) void k_aggregate3(
    const int* __restrict__ rp, const int* __restrict__ csrc,
    const float* __restrict__ el, const float* __restrict__ er,
    const _Float16* __restrict__ Z, const float* __restrict__ bias,
    float* __restrict__ out) {
  int wid = (blockIdx.x * 256 + threadIdx.x) >> 6;
  if (wid >= NN) return;
  int lane = threadIdx.x & 63;
  int h = lane >> 4;
  int c0 = lane * 4;
  int beg = rp[wid], end = rp[wid + 1];
  int deg = end - beg;
  float4 bv = *reinterpret_cast<const float4*>(bias + c0);
  size_t optr = (size_t)wid * HF + c0;
  if (deg == 0) {
    *reinterpret_cast<float4*>(out + optr) = bv;
    return;
  }
  float4 acc = {0.f, 0.f, 0.f, 0.f};
  float inv;
  if (deg <= 64) {
    // ---- pass A: lane i owns edge i ----
    int s = 0;
    float4 x = {-1e30f, -1e30f, -1e30f, -1e30f};
    float4 b = *reinterpret_cast<const float4*>(er + (size_t)wid * 4);
    if (lane < deg) {
      s = csrc[beg + lane];
      float4 a = reinterpret_cast<const float4*>(el)[s];
      x.x = a.x + b.x; x.x = x.x >= 0.f ? x.x : 0.2f * x.x;
      x.y = a.y + b.y; x.y = x.y >= 0.f ? x.y : 0.2f * x.y;
      x.z = a.z + b.z; x.z = x.z >= 0.f ? x.z : 0.2f * x.z;
      x.w = a.w + b.w; x.w = x.w >= 0.f ? x.w : 0.2f * x.w;
    }
    float4 m = x;
#pragma unroll
    for (int off = 32; off > 0; off >>= 1) {
      m.x = fmaxf(m.x, __shfl_xor(m.x, off));
      m.y = fmaxf(m.y, __shfl_xor(m.y, off));
      m.z = fmaxf(m.z, __shfl_xor(m.z, off));
      m.w = fmaxf(m.w, __shfl_xor(m.w, off));
    }
    float4 ex = {0.f, 0.f, 0.f, 0.f};
    if (lane < deg) {
      ex.x = __expf(x.x - m.x);
      ex.y = __expf(x.y - m.y);
      ex.z = __expf(x.z - m.z);
      ex.w = __expf(x.w - m.w);
    }
    float4 sm = ex;
#pragma unroll
    for (int off = 32; off > 0; off >>= 1) {
      sm.x += __shfl_xor(sm.x, off);
      sm.y += __shfl_xor(sm.y, off);
      sm.z += __shfl_xor(sm.z, off);
      sm.w += __shfl_xor(sm.w, off);
    }
    inv = 1.0f / pick_h(sm, h);
    // ---- pass B: 4 independent Z-row gathers in flight ----
    int i = 0;
    for (; i + 4 <= deg; i += 4) {
      int s0 = __shfl(s, i), s1 = __shfl(s, i + 1), s2 = __shfl(s, i + 2), s3 = __shfl(s, i + 3);
      float4 w4;
      w4.x = pick_h((float4){__shfl(ex.x, i), __shfl(ex.y, i), __shfl(ex.z, i), __shfl(ex.w, i)}, h);
      w4.y = pick_h((float4){__shfl(ex.x, i + 1), __shfl(ex.y, i + 1), __shfl(ex.z, i + 1), __shfl(ex.w, i + 1)}, h);
      w4.z = pick_h((float4){__shfl(ex.x, i + 2), __shfl(ex.y, i + 2), __shfl(ex.z, i + 2), __shfl(ex.w, i + 2)}, h);
      w4.w = pick_h((float4){__shfl(ex.x, i + 3), __shfl(ex.y, i + 3), __shfl(ex.z, i + 3), __shfl(ex.w, i + 3)}, h);
      f16x4 z0 = *reinterpret_cast<const f16x4*>(Z + (size_t)s0 * HF + c0);
      f16x4 z1 = *reinterpret_cast<const f16x4*>(Z + (size_t)s1 * HF + c0);
      f16x4 z2 = *reinterpret_cast<const f16x4*>(Z + (size_t)s2 * HF + c0);
      f16x4 z3 = *reinterpret_cast<const f16x4*>(Z + (size_t)s3 * HF + c0);
      acc.x += w4.x * (float)z0.x + w4.y * (float)z1.x + w4.z * (float)z2.x + w4.w * (float)z3.x;
      acc.y += w4.x * (float)z0.y + w4.y * (float)z1.y + w4.z * (float)z2.y + w4.w * (float)z3.y;
      acc.z += w4.x * (float)z0.z + w4.y * (float)z1.z + w4.z * (float)z2.z + w4.w * (float)z3.z;
      acc.w += w4.x * (float)z0.w + w4.y * (float)z1.w + w4.z * (float)z2.w + w4.w * (float)z3.w;
    }
    for (; i < deg; ++i) {
      int s0 = __shfl(s, i);
      float w0 = pick_h((float4){__shfl(ex.x, i), __shfl(ex.y, i), __shfl(ex.z, i), __shfl(ex.w, i)}, h);
      f16x4 z0 = *reinterpret_cast<const f16x4*>(Z + (size_t)s0 * HF + c0);
      acc.x += w0 * (float)z0.x;
      acc.y += w0 * (float)z0.y;
      acc.z += w0 * (float)z0.z;
      acc.w += w0 * (float)z0.w;
    }
  } else {
    // ---- rare fallback (deg > 64): uniform two-pass ----
    float4 b = *reinterpret_cast<const float4*>(er + (size_t)wid * 4);
    float4 m = {-1e30f, -1e30f, -1e30f, -1e30f};
    for (int e = beg; e < end; ++e) {
      int s = csrc[e];
      float4 a = reinterpret_cast<const float4*>(el)[s];
      float4 x;
      x.x = a.x + b.x; x.x = x.x >= 0.f ? x.x : 0.2f * x.x;
      x.y = a.y + b.y; x.y = x.y >= 0.f ? x.y : 0.2f * x.y;
      x.z = a.z + b.z; x.z = x.z >= 0.f ? x.z : 0.2f * x.z;
      x.w = a.w + b.w; x.w = x.w >= 0.f ? x.w : 0.2f * x.w;
      m.x = fmaxf(m.x, x.x); m.y = fmaxf(m.y, x.y);
      m.z = fmaxf(m.z, x.z); m.w = fmaxf(m.w, x.w);
    }
    float4 sm = {0.f, 0.f, 0.f, 0.f};
    for (int e = beg; e < end; ++e) {
      int s = csrc[e];
      float4 a = reinterpret_cast<const float4*>(el)[s];
      float4 x;
      x.x = a.x + b.x; x.x = x.x >= 0.f ? x.x : 0.2f * x.x;
      x.y = a.y + b.y; x.y = x.y >= 0.f ? x.y : 0.2f * x.y;
      x.z = a.z + b.z; x.z = x.z >= 0.f ? x.z : 0.2f * x.z;
      x.w = a.w + b.w; x.w = x.w >= 0.f ? x.w : 0.2f * x.w;
      float4 ex;
      ex.x = __expf(x.x - m.x); ex.y = __expf(x.y - m.y);
      ex.z = __expf(x.z - m.z); ex.w = __expf(x.w - m.w);
      sm.x += ex.x; sm.y += ex.y; sm.z += ex.z; sm.w += ex.w;
      float w0 = pick_h(ex, h);
      f16x4 z0 = *reinterpret_cast<const f16x4*>(Z + (size_t)s * HF + c0);
      acc.x += w0 * (float)z0.x;
      acc.y += w0 * (float)z0.y;
      acc.z += w0 * (float)z0.z;
      acc.w += w0 * (float)z0.w;
    }
    inv = 1.0f / pick_h(sm, h);
  }
  float4 r;
  r.x = acc.x * inv + bv.x;
  r.y = acc.y * inv + bv.y;
  r.z = acc.z * inv + bv.z;
  r.w = acc.w * inv + bv.w;
  *reinterpret_cast<float4*>(out + optr) = r;
}

// ---------- batchnorm ----------
__global__ __launch_bounds__(256) void k_bn_stats(const float* __restrict__ X,
                                                  float* __restrict__ sums, float* __restrict__ sqs) {
  int c = threadIdx.x;
  float s = 0.f, q = 0.f;
  for (int r = blockIdx.x; r < NN; r += gridDim.x) {
    float v = X[(size_t)r * HF + c];
    s += v;
    q += v * v;
  }
  atomicAdd(&sums[c], s);
  atomicAdd(&sqs[c], q);
}

__global__ __launch_bounds__(256) void k_bn_apply(const float* __restrict__ X,
    const float* __restrict__ sums, const float* __restrict__ sqs,
    const float* __restrict__ g, const float* __restrict__ bt,
    _Float16* __restrict__ Y, int act) {
  int idx = blockIdx.x * 256 + threadIdx.x;  // grid = NN blocks
  int c = idx & 255;
  const float invN = 1.0f / NN;
  float mu = sums[c] * invN;
  float var = sqs[c] * invN - mu * mu;
  float sc = rsqrtf(var + 1e-5f) * g[c];
  float v = (X[idx] - mu) * sc + bt[c];
  v = act ? tanhf(v) : (v >= 0.f ? v : 0.01f * v);
  Y[idx] = (_Float16)v;
}

extern "C" void kernel_launch(void* const* d_in, const int* in_sizes, int n_in,
                              void* d_out, int out_size, void* d_ws, size_t ws_size,
                              hipStream_t stream) {
  (void)in_sizes; (void)n_in; (void)out_size; (void)ws_size;
  const float* x_user = (const float*)d_in[0];
  const float* x_item = (const float*)d_in[1];
  const int* ui_src = (const int*)d_in[2];
  const int* ui_dst = (const int*)d_in[3];
  const int* iu_src = (const int*)d_in[4];
  const int* iu_dst = (const int*)d_in[5];
  const float *Wp[4], *alp[4], *arp[4], *bp[4];
  for (int l = 0; l < 4; ++l) {
    Wp[l]  = (const float*)d_in[6 + 4 * l];
    alp[l] = (const float*)d_in[7 + 4 * l];
    arp[l] = (const float*)d_in[8 + 4 * l];
    bp[l]  = (const float*)d_in[9 + 4 * l];
  }
  const float* bng = (const float*)d_in[22];
  const float* bnb = (const float*)d_in[23];

  char* w = (char*)d_ws;
  auto alloc = [&](size_t bytes) -> void* {
    void* p = (void*)w;
    w += (bytes + 255) & ~(size_t)255;
    return p;
  };
  _Float16* XU16 = (_Float16*)alloc((size_t)NN * 128 * 2);
  _Float16* XI16 = (_Float16*)alloc((size_t)NN * 128 * 2);
  _Float16* H16U = (_Float16*)alloc((size_t)NN * HF * 2);
  _Float16* H16I = (_Float16*)alloc((size_t)NN * HF * 2);
  _Float16* Z = (_Float16*)alloc((size_t)NN * HF * 2);
  float* RAWU = (float*)alloc((size_t)NN * HF * 4);
  float* RAWI = (float*)alloc((size_t)NN * HF * 4);
  float* EL0 = (float*)alloc((size_t)NN * 4 * 4);
  float* ER0 = (float*)alloc((size_t)NN * 4 * 4);
  float* EL1 = (float*)alloc((size_t)NN * 4 * 4);
  float* ER1 = (float*)alloc((size_t)NN * 4 * 4);
  _Float16* WT = (_Float16*)alloc((size_t)8 * 65536 * 2);
  float* ATTN = (float*)alloc((size_t)4 * 256 * 4 * 4);
  int* rp_ui = (int*)alloc((size_t)(NN + 1) * 4);
  int* rp_iu = (int*)alloc((size_t)(NN + 1) * 4);
  int* csrc_ui = (int*)alloc((size_t)NE * 4);
  int* csrc_iu = (int*)alloc((size_t)NE * 4);
  int* counts = (int*)alloc((size_t)4 * NN * 4);  // counts_ui | counts_iu | fill_ui | fill_iu
  int* bsum_ui = (int*)alloc((size_t)64 * 4);
  int* bsum_iu = (int*)alloc((size_t)64 * 4);
  float* stats = (float*)alloc((size_t)6 * 512 * 4);

  int* counts_ui = counts;
  int* counts_iu = counts + NN;
  int* fill_ui = counts + 2 * NN;
  int* fill_iu = counts + 3 * NN;

  hipMemsetAsync(counts, 0, (size_t)4 * NN * 4, stream);
  hipMemsetAsync(stats, 0, (size_t)6 * 512 * 4, stream);

  // input conversion + weight transposes (once per call)
  k_tofp16<<<(NN * 128 / 4 + 255) / 256, 256, 0, stream>>>(x_user, XU16, NN * 128 / 4);
  k_tofp16<<<(NN * 128 / 4 + 255) / 256, 256, 0, stream>>>(x_item, XI16, NN * 128 / 4);
  for (int l = 0; l < 4; ++l) {
    int K = (l == 0) ? 128 : 256;
    for (int r = 0; r < 2; ++r)
      k_transpose<<<K, 256, 0, stream>>>(Wp[l] + (size_t)r * K * HF, WT + (size_t)(l * 2 + r) * 65536, K);
  }
  // CSR builds (edges shared by all layers)
  int egrid = (NE + 255) / 256;
  int nscan = (NN + 1023) / 1024;
  k_hist<<<egrid, 256, 0, stream>>>(ui_dst, counts_ui);
  k_hist<<<egrid, 256, 0, stream>>>(iu_dst, counts_iu);
  k_scan1<<<nscan, 1024, 0, stream>>>(counts_ui, rp_ui, bsum_ui);
  k_scan2<<<1, 64, 0, stream>>>(bsum_ui, nscan);
  k_scan3<<<nscan, 1024, 0, stream>>>(rp_ui, bsum_ui);
  k_scan1<<<nscan, 1024, 0, stream>>>(counts_iu, rp_iu, bsum_iu);
  k_scan2<<<1, 64, 0, stream>>>(bsum_iu, nscan);
  k_scan3<<<nscan, 1024, 0, stream>>>(rp_iu, bsum_iu);
  k_scatter<<<egrid, 256, 0, stream>>>(ui_src, ui_dst, rp_ui, fill_ui, csrc_ui);
  k_scatter<<<egrid, 256, 0, stream>>>(iu_src, iu_dst, rp_iu, fill_iu, csrc_iu);

  const _Float16* hu16 = XU16;
  const _Float16* hi16 = XI16;
  int mgrid = (NN + 63) / 64;
  int agrid = (NN + 3) / 4;
  float* out_user = (float*)d_out;
  float* out_item = (float*)d_out + (size_t)NN * HF;

  for (int l = 0; l < 4; ++l) {
    int K = (l == 0) ? 128 : 256;
    const _Float16* W0t = WT + (size_t)(l * 2 + 0) * 65536;
    const _Float16* W1t = WT + (size_t)(l * 2 + 1) * 65536;

    // attn projection tables: wal0 | war0 | wal1 | war1, each [K][4]
    k_makeattn<<<(4 * K * 4 + 255) / 256, 256, 0, stream>>>(Wp[l], alp[l], arp[l], K, ATTN);
    // hu -> el_ui (wal0), er_iu (war1); hi -> er_ui (war0), el_iu (wal1)
    k_gemv4<<<agrid, 256, 0, stream>>>(hu16, ATTN + 0 * K * 4, ATTN + 3 * K * 4, EL0, ER1, K);
    k_gemv4<<<agrid, 256, 0, stream>>>(hi16, ATTN + 1 * K * 4, ATTN + 2 * K * 4, ER0, EL1, K);

    // relation u->i (dst = items): z_src = hu@W0
    k_gemm<<<mgrid, 256, 0, stream>>>(hu16, W0t, Z, NN, K);
    k_aggregate3<<<agrid, 256, 0, stream>>>(rp_ui, csrc_ui, EL0, ER0, Z, bp[l] + 0,
                                            (l < 3) ? RAWI : out_item);

    // relation i->u (dst = users): z_src = hi@W1
    k_gemm<<<mgrid, 256, 0, stream>>>(hi16, W1t, Z, NN, K);
    k_aggregate3<<<agrid, 256, 0, stream>>>(rp_iu, csrc_iu, EL1, ER1, Z, bp[l] + 256,
                                            (l < 3) ? RAWU : out_user);

    if (l < 3) {
      int act = (l == 2) ? 1 : 0;
      float* su = stats + (size_t)(l * 2 + 0) * 512;
      float* qu = su + 256;
      float* si = stats + (size_t)(l * 2 + 1) * 512;
      float* qi = si + 256;
      k_bn_stats<<<512, 256, 0, stream>>>(RAWU, su, qu);
      k_bn_stats<<<512, 256, 0, stream>>>(RAWI, si, qi);
      k_bn_apply<<<NN, 256, 0, stream>>>(RAWU, su, qu, bng + (size_t)(l * 2 + 0) * 256,
                                         bnb + (size_t)(l * 2 + 0) * 256, H16U, act);
      k_bn_apply<<<NN, 256, 0, stream>>>(RAWI, si, qi, bng + (size_t)(l * 2 + 1) * 256,
                                         bnb + (size_t)(l * 2 + 1) * 256, H16I, act);
      hu16 = H16U;
      hi16 = H16I;
    }
  }
}

// Round 6
// 1394.951 us; speedup vs baseline: 2.3383x; 1.0778x over previous
//
#include <hip/hip_runtime.h>
#include <hip/hip_bf16.h>
#include <type_traits>

#define NN 50000     // nodes per side (users == items == 50000)
#define NE 600000    // edges per relation
#define HF 256       // hidden features

typedef float f32x4 __attribute__((ext_vector_type(4)));
typedef _Float16 f16x8 __attribute__((ext_vector_type(8)));
typedef _Float16 f16x4 __attribute__((ext_vector_type(4)));

// ---------- fp32 -> fp16 convert ----------
__global__ __launch_bounds__(256) void k_tofp16(const float* __restrict__ X,
                                                _Float16* __restrict__ Y, int n4) {
  int i = blockIdx.x * 256 + threadIdx.x;
  if (i < n4) {
    float4 v = reinterpret_cast<const float4*>(X)[i];
    f16x4 o = {(_Float16)v.x, (_Float16)v.y, (_Float16)v.z, (_Float16)v.w};
    reinterpret_cast<f16x4*>(Y)[i] = o;
  }
}

// ---------- W[K][256] (fp32) -> Wt[256][K] (fp16) ----------
__global__ __launch_bounds__(256) void k_transpose(const float* __restrict__ W,
                                                   _Float16* __restrict__ Wt, int K) {
  int idx = blockIdx.x * 256 + threadIdx.x;
  if (idx >= K * 256) return;
  int k = idx >> 8;
  int n = idx & 255;
  Wt[(size_t)n * K + k] = (_Float16)W[idx];
}

// ---------- attn projections: out[combo][k][h] = sum_d W[combo>>1][k, h*64+d] * a[h*64+d] ----------
__global__ __launch_bounds__(256) void k_makeattn(const float* __restrict__ Wfull,  // [2,K,256]
                                                  const float* __restrict__ al,    // [2,256]
                                                  const float* __restrict__ ar,    // [2,256]
                                                  int K, float* __restrict__ out) {
  int idx = blockIdx.x * 256 + threadIdx.x;
  if (idx >= 4 * K * 4) return;
  int h = idx & 3;
  int k = (idx >> 2) % K;
  int combo = idx / (4 * K);
  const float* W = Wfull + (size_t)(combo >> 1) * K * 256;
  const float* a = ((combo & 1) ? ar : al) + (combo >> 1) * 256 + h * 64;
  const float* wrow = W + (size_t)k * 256 + h * 64;
  float s = 0.f;
#pragma unroll 8
  for (int d = 0; d < 64; ++d) s += wrow[d] * a[d];
  out[(size_t)combo * K * 4 + k * 4 + h] = s;
}

// ---------- dual GEMV (X fp16): one wave per row ----------
__global__ __launch_bounds__(256) void k_gemv4(const _Float16* __restrict__ X,
                                               const float* __restrict__ wa,  // [K][4]
                                               const float* __restrict__ wb,  // [K][4]
                                               float* __restrict__ outA, float* __restrict__ outB,
                                               int K) {
  int wid = (blockIdx.x * 256 + threadIdx.x) >> 6;
  if (wid >= NN) return;
  int lane = threadIdx.x & 63;
  float pa0 = 0.f, pa1 = 0.f, pa2 = 0.f, pa3 = 0.f;
  float pb0 = 0.f, pb1 = 0.f, pb2 = 0.f, pb3 = 0.f;
  int k0 = lane * 4;
  if (k0 < K) {
    f16x4 x = *reinterpret_cast<const f16x4*>(X + (size_t)wid * K + k0);
    float xv[4] = {(float)x.x, (float)x.y, (float)x.z, (float)x.w};
#pragma unroll
    for (int j = 0; j < 4; ++j) {
      float4 wav = *reinterpret_cast<const float4*>(wa + (k0 + j) * 4);
      float4 wbv = *reinterpret_cast<const float4*>(wb + (k0 + j) * 4);
      pa0 += xv[j] * wav.x; pa1 += xv[j] * wav.y; pa2 += xv[j] * wav.z; pa3 += xv[j] * wav.w;
      pb0 += xv[j] * wbv.x; pb1 += xv[j] * wbv.y; pb2 += xv[j] * wbv.z; pb3 += xv[j] * wbv.w;
    }
  }
#pragma unroll
  for (int off = 32; off > 0; off >>= 1) {
    pa0 += __shfl_down(pa0, off); pa1 += __shfl_down(pa1, off);
    pa2 += __shfl_down(pa2, off); pa3 += __shfl_down(pa3, off);
    pb0 += __shfl_down(pb0, off); pb1 += __shfl_down(pb1, off);
    pb2 += __shfl_down(pb2, off); pb3 += __shfl_down(pb3, off);
  }
  if (lane == 0) {
    *reinterpret_cast<float4*>(outA + (size_t)wid * 4) = (float4){pa0, pa1, pa2, pa3};
    *reinterpret_cast<float4*>(outB + (size_t)wid * 4) = (float4){pb0, pb1, pb2, pb3};
  }
}

// ---------- GEMM: Z[M,256](fp16) = A[M,K](fp16) @ W[K,256] ----------
__global__ __launch_bounds__(256) void k_gemm(const _Float16* __restrict__ A,
                                              const _Float16* __restrict__ Wt,
                                              _Float16* __restrict__ Z,
                                              int M, int K) {
  int wave = threadIdx.x >> 6;
  int lane = threadIdx.x & 63;
  int lr = lane & 15;   // fragment row (A) / col (B)
  int kg = lane >> 4;   // k-group: k = kg*8 + j
  int row0 = blockIdx.x * 64;
  int col0 = wave * 64;
  f32x4 acc[4][4];
#pragma unroll
  for (int i = 0; i < 4; ++i)
#pragma unroll
    for (int j = 0; j < 4; ++j) acc[i][j] = (f32x4){0.f, 0.f, 0.f, 0.f};

  for (int k0 = 0; k0 < K; k0 += 32) {
    f16x8 af[4], bfr[4];
#pragma unroll
    for (int mt = 0; mt < 4; ++mt) {
      int r = row0 + mt * 16 + lr;
      if (r >= M) r = M - 1;  // clamp loads; stores are guarded
      af[mt] = *reinterpret_cast<const f16x8*>(A + (size_t)r * K + k0 + kg * 8);
    }
#pragma unroll
    for (int ct = 0; ct < 4; ++ct) {
      int c = col0 + ct * 16 + lr;
      bfr[ct] = *reinterpret_cast<const f16x8*>(Wt + (size_t)c * K + k0 + kg * 8);
    }
#pragma unroll
    for (int mt = 0; mt < 4; ++mt)
#pragma unroll
      for (int ct = 0; ct < 4; ++ct)
        acc[mt][ct] = __builtin_amdgcn_mfma_f32_16x16x32_f16(af[mt], bfr[ct], acc[mt][ct], 0, 0, 0);
  }
  // C/D layout: col = lane&15, row = (lane>>4)*4 + reg
#pragma unroll
  for (int mt = 0; mt < 4; ++mt) {
#pragma unroll
    for (int r = 0; r < 4; ++r) {
      int row = row0 + mt * 16 + kg * 4 + r;
      if (row < M) {
#pragma unroll
        for (int ct = 0; ct < 4; ++ct) {
          int col = col0 + ct * 16 + lr;
          Z[(size_t)row * HF + col] = (_Float16)acc[mt][ct][r];
        }
      }
    }
  }
}

// ---------- CSR build ----------
__global__ __launch_bounds__(256) void k_hist(const int* __restrict__ dst, int* __restrict__ counts) {
  int e = blockIdx.x * 256 + threadIdx.x;
  if (e < NE) atomicAdd(&counts[dst[e]], 1);
}

__global__ __launch_bounds__(1024) void k_scan1(const int* __restrict__ counts,
                                                int* __restrict__ rp, int* __restrict__ bsum) {
  __shared__ int tmp[1024];
  int i = blockIdx.x * 1024 + threadIdx.x;
  int v = (i < NN) ? counts[i] : 0;
  tmp[threadIdx.x] = v;
  __syncthreads();
  for (int off = 1; off < 1024; off <<= 1) {
    int t = (threadIdx.x >= off) ? tmp[threadIdx.x - off] : 0;
    __syncthreads();
    tmp[threadIdx.x] += t;
    __syncthreads();
  }
  if (i < NN) rp[i] = tmp[threadIdx.x] - v;  // block-local exclusive
  if (threadIdx.x == 1023) bsum[blockIdx.x] = tmp[1023];
}

__global__ __launch_bounds__(64) void k_scan2(int* __restrict__ bsum, int nb) {
  int l = threadIdx.x;
  int orig = (l < nb) ? bsum[l] : 0;
  int v = orig;
#pragma unroll
  for (int off = 1; off < 64; off <<= 1) {
    int t = __shfl_up(v, off);
    if (l >= off) v += t;
  }
  if (l < nb) bsum[l] = v - orig;  // exclusive
}

__global__ __launch_bounds__(1024) void k_scan3(int* __restrict__ rp, const int* __restrict__ bsum) {
  int i = blockIdx.x * 1024 + threadIdx.x;
  if (i < NN) rp[i] += bsum[blockIdx.x];
  if (i == 0) rp[NN] = NE;
}

__global__ __launch_bounds__(256) void k_scatter(const int* __restrict__ src, const int* __restrict__ dst,
                                                 const int* __restrict__ rp, int* __restrict__ fill,
                                                 int* __restrict__ csrc) {
  int e = blockIdx.x * 256 + threadIdx.x;
  if (e < NE) {
    int d = dst[e];
    int pos = rp[d] + atomicAdd(&fill[d], 1);
    csrc[pos] = src[e];
  }
}

__device__ __forceinline__ float pick_h(float4 v, int h) {
  float r = v.x;
  r = (h == 1) ? v.y : r;
  r = (h == 2) ? v.z : r;
  r = (h == 3) ? v.w : r;
  return r;
}

// ---------- fused GAT aggregation v4 ----------
// wave per dst; pass A: lane i owns edge i, softmax via shfl butterflies, ex+src staged in LDS.
// pass B: half-wave per edge (lane owns 8 cols, f16x8), 4-group unroll -> 8 gathers in flight.
template <typename OT>
__global__ __launch_bounds__(256) void k_aggregate4(
    const int* __restrict__ rp, const int* __restrict__ csrc,
    const float* __restrict__ el, const float* __restrict__ er,
    const _Float16* __restrict__ Z, const float* __restrict__ bias,
    OT* __restrict__ out) {
  __shared__ float exs[4][256];
  __shared__ int ssrc[4][64];
  int wv = threadIdx.x >> 6;
  int wid = blockIdx.x * 4 + wv;
  if (wid >= NN) return;
  int lane = threadIdx.x & 63;
  int half = lane >> 5, l5 = lane & 31;
  int c0 = l5 * 8;      // 8 cols per lane (halves cover full row)
  int h = l5 >> 3;      // head for cols c0..c0+7
  int beg = rp[wid], end = rp[wid + 1];
  int deg = end - beg;

  if (deg == 0) {
    if (half == 0) {
      float4 b0 = *reinterpret_cast<const float4*>(bias + c0);
      float4 b1 = *reinterpret_cast<const float4*>(bias + c0 + 4);
      if constexpr (std::is_same<OT, float>::value) {
        float4* op = reinterpret_cast<float4*>(out + (size_t)wid * HF + c0);
        op[0] = b0; op[1] = b1;
      } else {
        f16x8 o = {(_Float16)b0.x, (_Float16)b0.y, (_Float16)b0.z, (_Float16)b0.w,
                   (_Float16)b1.x, (_Float16)b1.y, (_Float16)b1.z, (_Float16)b1.w};
        *reinterpret_cast<f16x8*>(out + (size_t)wid * HF + c0) = o;
      }
    }
    return;
  }

  if (deg <= 64) {
    // ---- pass A ----
    int s = 0;
    float4 x = {-1e30f, -1e30f, -1e30f, -1e30f};
    float4 b = *reinterpret_cast<const float4*>(er + (size_t)wid * 4);
    if (lane < deg) {
      s = csrc[beg + lane];
      float4 a = reinterpret_cast<const float4*>(el)[s];
      x.x = a.x + b.x; x.x = x.x >= 0.f ? x.x : 0.2f * x.x;
      x.y = a.y + b.y; x.y = x.y >= 0.f ? x.y : 0.2f * x.y;
      x.z = a.z + b.z; x.z = x.z >= 0.f ? x.z : 0.2f * x.z;
      x.w = a.w + b.w; x.w = x.w >= 0.f ? x.w : 0.2f * x.w;
    }
    float4 m = x;
#pragma unroll
    for (int off = 32; off > 0; off >>= 1) {
      m.x = fmaxf(m.x, __shfl_xor(m.x, off));
      m.y = fmaxf(m.y, __shfl_xor(m.y, off));
      m.z = fmaxf(m.z, __shfl_xor(m.z, off));
      m.w = fmaxf(m.w, __shfl_xor(m.w, off));
    }
    float4 ex = {0.f, 0.f, 0.f, 0.f};
    if (lane < deg) {
      ex.x = __expf(x.x - m.x);
      ex.y = __expf(x.y - m.y);
      ex.z = __expf(x.z - m.z);
      ex.w = __expf(x.w - m.w);
    }
    float4 sm = ex;
#pragma unroll
    for (int off = 32; off > 0; off >>= 1) {
      sm.x += __shfl_xor(sm.x, off);
      sm.y += __shfl_xor(sm.y, off);
      sm.z += __shfl_xor(sm.z, off);
      sm.w += __shfl_xor(sm.w, off);
    }
    float inv = 1.0f / pick_h(sm, h);
    if (lane < deg) {
      *reinterpret_cast<float4*>(&exs[wv][lane * 4]) = ex;
      ssrc[wv][lane] = s;
    }
    // ---- pass B: halves own alternate edges, 4-group unroll ----
    float a8[8] = {0.f, 0.f, 0.f, 0.f, 0.f, 0.f, 0.f, 0.f};
    int j = half;
#define AGG_STEP(J)                                                        \
    {                                                                      \
      int sj = ssrc[wv][(J)];                                              \
      float wj = exs[wv][(J) * 4 + h];                                     \
      f16x8 z = *reinterpret_cast<const f16x8*>(Z + (size_t)sj * HF + c0); \
      _Pragma("unroll")                                                    \
      for (int q = 0; q < 8; ++q) a8[q] += wj * (float)z[q];               \
    }
    for (; j + 6 < deg; j += 8) {
      AGG_STEP(j); AGG_STEP(j + 2); AGG_STEP(j + 4); AGG_STEP(j + 6);
    }
    for (; j < deg; j += 2) { AGG_STEP(j); }
#undef AGG_STEP
#pragma unroll
    for (int q = 0; q < 8; ++q) a8[q] += __shfl_xor(a8[q], 32);
    if (half == 0) {
      float4 b0 = *reinterpret_cast<const float4*>(bias + c0);
      float4 b1 = *reinterpret_cast<const float4*>(bias + c0 + 4);
      float r0 = a8[0] * inv + b0.x, r1 = a8[1] * inv + b0.y;
      float r2 = a8[2] * inv + b0.z, r3 = a8[3] * inv + b0.w;
      float r4 = a8[4] * inv + b1.x, r5 = a8[5] * inv + b1.y;
      float r6 = a8[6] * inv + b1.z, r7 = a8[7] * inv + b1.w;
      if constexpr (std::is_same<OT, float>::value) {
        float4* op = reinterpret_cast<float4*>(out + (size_t)wid * HF + c0);
        op[0] = (float4){r0, r1, r2, r3};
        op[1] = (float4){r4, r5, r6, r7};
      } else {
        f16x8 o = {(_Float16)r0, (_Float16)r1, (_Float16)r2, (_Float16)r3,
                   (_Float16)r4, (_Float16)r5, (_Float16)r6, (_Float16)r7};
        *reinterpret_cast<f16x8*>(out + (size_t)wid * HF + c0) = o;
      }
    }
    return;
  }

  // ---- rare fallback (deg > 64): uniform two-pass, full-wave f16x4 mapping ----
  {
    int c4 = lane * 4;
    int h4 = lane >> 4;
    float4 b = *reinterpret_cast<const float4*>(er + (size_t)wid * 4);
    float4 m = {-1e30f, -1e30f, -1e30f, -1e30f};
    for (int e = beg; e < end; ++e) {
      int s = csrc[e];
      float4 a = reinterpret_cast<const float4*>(el)[s];
      float4 x;
      x.x = a.x + b.x; x.x = x.x >= 0.f ? x.x : 0.2f * x.x;
      x.y = a.y + b.y; x.y = x.y >= 0.f ? x.y : 0.2f * x.y;
      x.z = a.z + b.z; x.z = x.z >= 0.f ? x.z : 0.2f * x.z;
      x.w = a.w + b.w; x.w = x.w >= 0.f ? x.w : 0.2f * x.w;
      m.x = fmaxf(m.x, x.x); m.y = fmaxf(m.y, x.y);
      m.z = fmaxf(m.z, x.z); m.w = fmaxf(m.w, x.w);
    }
    float4 sm = {0.f, 0.f, 0.f, 0.f};
    float4 acc = {0.f, 0.f, 0.f, 0.f};
    for (int e = beg; e < end; ++e) {
      int s = csrc[e];
      float4 a = reinterpret_cast<const float4*>(el)[s];
      float4 x;
      x.x = a.x + b.x; x.x = x.x >= 0.f ? x.x : 0.2f * x.x;
      x.y = a.y + b.y; x.y = x.y >= 0.f ? x.y : 0.2f * x.y;
      x.z = a.z + b.z; x.z = x.z >= 0.f ? x.z : 0.2f * x.z;
      x.w = a.w + b.w; x.w = x.w >= 0.f ? x.w : 0.2f * x.w;
      float4 exv;
      exv.x = __expf(x.x - m.x); exv.y = __expf(x.y - m.y);
      exv.z = __expf(x.z - m.z); exv.w = __expf(x.w - m.w);
      sm.x += exv.x; sm.y += exv.y; sm.z += exv.z; sm.w += exv.w;
      float w0 = pick_h(exv, h4);
      f16x4 z0 = *reinterpret_cast<const f16x4*>(Z + (size_t)s * HF + c4);
      acc.x += w0 * (float)z0.x;
      acc.y += w0 * (float)z0.y;
      acc.z += w0 * (float)z0.z;
      acc.w += w0 * (float)z0.w;
    }
    float inv = 1.0f / pick_h(sm, h4);
    float4 bv = *reinterpret_cast<const float4*>(bias + c4);
    float r0 = acc.x * inv + bv.x, r1 = acc.y * inv + bv.y;
    float r2 = acc.z * inv + bv.z, r3 = acc.w * inv + bv.w;
    if constexpr (std::is_same<OT, float>::value) {
      *reinterpret_cast<float4*>(out + (size_t)wid * HF + c4) = (float4){r0, r1, r2, r3};
    } else {
      f16x4 o = {(_Float16)r0, (_Float16)r1, (_Float16)r2, (_Float16)r3};
      *reinterpret_cast<f16x4*>(out + (size_t)wid * HF + c4) = o;
    }
  }
}

// ---------- batchnorm (fp16 raw input) ----------
__global__ __launch_bounds__(256) void k_bn_stats16(const _Float16* __restrict__ X,
                                                    float* __restrict__ sums, float* __restrict__ sqs) {
  int c = threadIdx.x;
  float s = 0.f, q = 0.f;
  for (int r = blockIdx.x; r < NN; r += gridDim.x) {
    float v = (float)X[(size_t)r * HF + c];
    s += v;
    q += v * v;
  }
  atomicAdd(&sums[c], s);
  atomicAdd(&sqs[c], q);
}

__global__ __launch_bounds__(256) void k_bn_apply16(const _Float16* __restrict__ X,
    const float* __restrict__ sums, const float* __restrict__ sqs,
    const float* __restrict__ g, const float* __restrict__ bt,
    _Float16* __restrict__ Y, int act) {
  int gid = blockIdx.x * 256 + threadIdx.x;  // grid = NN/8 blocks; thread owns 8 cols
  int i0 = gid * 8;
  int c0 = i0 & 255;
  const float invN = 1.0f / NN;
  f16x8 xv = *reinterpret_cast<const f16x8*>(X + i0);
  float4 s0 = *reinterpret_cast<const float4*>(sums + c0);
  float4 s1 = *reinterpret_cast<const float4*>(sums + c0 + 4);
  float4 q0 = *reinterpret_cast<const float4*>(sqs + c0);
  float4 q1 = *reinterpret_cast<const float4*>(sqs + c0 + 4);
  float4 g0 = *reinterpret_cast<const float4*>(g + c0);
  float4 g1 = *reinterpret_cast<const float4*>(g + c0 + 4);
  float4 b0 = *reinterpret_cast<const float4*>(bt + c0);
  float4 b1 = *reinterpret_cast<const float4*>(bt + c0 + 4);
  float sa[8] = {s0.x, s0.y, s0.z, s0.w, s1.x, s1.y, s1.z, s1.w};
  float qa[8] = {q0.x, q0.y, q0.z, q0.w, q1.x, q1.y, q1.z, q1.w};
  float ga[8] = {g0.x, g0.y, g0.z, g0.w, g1.x, g1.y, g1.z, g1.w};
  float ba[8] = {b0.x, b0.y, b0.z, b0.w, b1.x, b1.y, b1.z, b1.w};
  f16x8 o;
#pragma unroll
  for (int j = 0; j < 8; ++j) {
    float mu = sa[j] * invN;
    float var = qa[j] * invN - mu * mu;
    float sc = rsqrtf(var + 1e-5f) * ga[j];
    float v = ((float)xv[j] - mu) * sc + ba[j];
    v = act ? tanhf(v) : (v >= 0.f ? v : 0.01f * v);
    o[j] = (_Float16)v;
  }
  *reinterpret_cast<f16x8*>(Y + i0) = o;
}

extern "C" void kernel_launch(void* const* d_in, const int* in_sizes, int n_in,
                              void* d_out, int out_size, void* d_ws, size_t ws_size,
                              hipStream_t stream) {
  (void)in_sizes; (void)n_in; (void)out_size; (void)ws_size;
  const float* x_user = (const float*)d_in[0];
  const float* x_item = (const float*)d_in[1];
  const int* ui_src = (const int*)d_in[2];
  const int* ui_dst = (const int*)d_in[3];
  const int* iu_src = (const int*)d_in[4];
  const int* iu_dst = (const int*)d_in[5];
  const float *Wp[4], *alp[4], *arp[4], *bp[4];
  for (int l = 0; l < 4; ++l) {
    Wp[l]  = (const float*)d_in[6 + 4 * l];
    alp[l] = (const float*)d_in[7 + 4 * l];
    arp[l] = (const float*)d_in[8 + 4 * l];
    bp[l]  = (const float*)d_in[9 + 4 * l];
  }
  const float* bng = (const float*)d_in[22];
  const float* bnb = (const float*)d_in[23];

  char* w = (char*)d_ws;
  auto alloc = [&](size_t bytes) -> void* {
    void* p = (void*)w;
    w += (bytes + 255) & ~(size_t)255;
    return p;
  };
  _Float16* XU16 = (_Float16*)alloc((size_t)NN * 128 * 2);
  _Float16* XI16 = (_Float16*)alloc((size_t)NN * 128 * 2);
  _Float16* H16U = (_Float16*)alloc((size_t)NN * HF * 2);
  _Float16* H16I = (_Float16*)alloc((size_t)NN * HF * 2);
  _Float16* Z = (_Float16*)alloc((size_t)NN * HF * 2);
  _Float16* RAW16U = (_Float16*)alloc((size_t)NN * HF * 2);
  _Float16* RAW16I = (_Float16*)alloc((size_t)NN * HF * 2);
  float* EL0 = (float*)alloc((size_t)NN * 4 * 4);
  float* ER0 = (float*)alloc((size_t)NN * 4 * 4);
  float* EL1 = (float*)alloc((size_t)NN * 4 * 4);
  float* ER1 = (float*)alloc((size_t)NN * 4 * 4);
  _Float16* WT = (_Float16*)alloc((size_t)8 * 65536 * 2);
  float* ATTN = (float*)alloc((size_t)4 * 256 * 4 * 4);
  int* rp_ui = (int*)alloc((size_t)(NN + 1) * 4);
  int* rp_iu = (int*)alloc((size_t)(NN + 1) * 4);
  int* csrc_ui = (int*)alloc((size_t)NE * 4);
  int* csrc_iu = (int*)alloc((size_t)NE * 4);
  int* counts = (int*)alloc((size_t)4 * NN * 4);  // counts_ui | counts_iu | fill_ui | fill_iu
  int* bsum_ui = (int*)alloc((size_t)64 * 4);
  int* bsum_iu = (int*)alloc((size_t)64 * 4);
  float* stats = (float*)alloc((size_t)6 * 512 * 4);

  int* counts_ui = counts;
  int* counts_iu = counts + NN;
  int* fill_ui = counts + 2 * NN;
  int* fill_iu = counts + 3 * NN;

  hipMemsetAsync(counts, 0, (size_t)4 * NN * 4, stream);
  hipMemsetAsync(stats, 0, (size_t)6 * 512 * 4, stream);

  // input conversion + weight transposes (once per call)
  k_tofp16<<<(NN * 128 / 4 + 255) / 256, 256, 0, stream>>>(x_user, XU16, NN * 128 / 4);
  k_tofp16<<<(NN * 128 / 4 + 255) / 256, 256, 0, stream>>>(x_item, XI16, NN * 128 / 4);
  for (int l = 0; l < 4; ++l) {
    int K = (l == 0) ? 128 : 256;
    for (int r = 0; r < 2; ++r)
      k_transpose<<<K, 256, 0, stream>>>(Wp[l] + (size_t)r * K * HF, WT + (size_t)(l * 2 + r) * 65536, K);
  }
  // CSR builds (edges shared by all layers)
  int egrid = (NE + 255) / 256;
  int nscan = (NN + 1023) / 1024;
  k_hist<<<egrid, 256, 0, stream>>>(ui_dst, counts_ui);
  k_hist<<<egrid, 256, 0, stream>>>(iu_dst, counts_iu);
  k_scan1<<<nscan, 1024, 0, stream>>>(counts_ui, rp_ui, bsum_ui);
  k_scan2<<<1, 64, 0, stream>>>(bsum_ui, nscan);
  k_scan3<<<nscan, 1024, 0, stream>>>(rp_ui, bsum_ui);
  k_scan1<<<nscan, 1024, 0, stream>>>(counts_iu, rp_iu, bsum_iu);
  k_scan2<<<1, 64, 0, stream>>>(bsum_iu, nscan);
  k_scan3<<<nscan, 1024, 0, stream>>>(rp_iu, bsum_iu);
  k_scatter<<<egrid, 256, 0, stream>>>(ui_src, ui_dst, rp_ui, fill_ui, csrc_ui);
  k_scatter<<<egrid, 256, 0, stream>>>(iu_src, iu_dst, rp_iu, fill_iu, csrc_iu);

  const _Float16* hu16 = XU16;
  const _Float16* hi16 = XI16;
  int mgrid = (NN + 63) / 64;
  int agrid = (NN + 3) / 4;
  float* out_user = (float*)d_out;
  float* out_item = (float*)d_out + (size_t)NN * HF;

  for (int l = 0; l < 4; ++l) {
    int K = (l == 0) ? 128 : 256;
    const _Float16* W0t = WT + (size_t)(l * 2 + 0) * 65536;
    const _Float16* W1t = WT + (size_t)(l * 2 + 1) * 65536;

    // attn projection tables: wal0 | war0 | wal1 | war1, each [K][4]
    k_makeattn<<<(4 * K * 4 + 255) / 256, 256, 0, stream>>>(Wp[l], alp[l], arp[l], K, ATTN);
    // hu -> el_ui (wal0), er_iu (war1); hi -> er_ui (war0), el_iu (wal1)
    k_gemv4<<<agrid, 256, 0, stream>>>(hu16, ATTN + 0 * K * 4, ATTN + 3 * K * 4, EL0, ER1, K);
    k_gemv4<<<agrid, 256, 0, stream>>>(hi16, ATTN + 1 * K * 4, ATTN + 2 * K * 4, ER0, EL1, K);

    // relation u->i (dst = items): z_src = hu@W0
    k_gemm<<<mgrid, 256, 0, stream>>>(hu16, W0t, Z, NN, K);
    if (l < 3)
      k_aggregate4<_Float16><<<agrid, 256, 0, stream>>>(rp_ui, csrc_ui, EL0, ER0, Z, bp[l] + 0, RAW16I);
    else
      k_aggregate4<float><<<agrid, 256, 0, stream>>>(rp_ui, csrc_ui, EL0, ER0, Z, bp[l] + 0, out_item);

    // relation i->u (dst = users): z_src = hi@W1
    k_gemm<<<mgrid, 256, 0, stream>>>(hi16, W1t, Z, NN, K);
    if (l < 3)
      k_aggregate4<_Float16><<<agrid, 256, 0, stream>>>(rp_iu, csrc_iu, EL1, ER1, Z, bp[l] + 256, RAW16U);
    else
      k_aggregate4<float><<<agrid, 256, 0, stream>>>(rp_iu, csrc_iu, EL1, ER1, Z, bp[l] + 256, out_user);

    if (l < 3) {
      int act = (l == 2) ? 1 : 0;
      float* su = stats + (size_t)(l * 2 + 0) * 512;
      float* qu = su + 256;
      float* si = stats + (size_t)(l * 2 + 1) * 512;
      float* qi = si + 256;
      k_bn_stats16<<<512, 256, 0, stream>>>(RAW16U, su, qu);
      k_bn_stats16<<<512, 256, 0, stream>>>(RAW16I, si, qi);
      k_bn_apply16<<<NN / 8, 256, 0, stream>>>(RAW16U, su, qu, bng + (size_t)(l * 2 + 0) * 256,
                                               bnb + (size_t)(l * 2 + 0) * 256, H16U, act);
      k_bn_apply16<<<NN / 8, 256, 0, stream>>>(RAW16I, si, qi, bng + (size_t)(l * 2 + 1) * 256,
                                               bnb + (size_t)(l * 2 + 1) * 256, H16I, act);
      hu16 = H16U;
      hi16 = H16I;
    }
  }
}

// Round 7
// 1125.182 us; speedup vs baseline: 2.8989x; 1.2398x over previous
//
#include <hip/hip_runtime.h>
#include <hip/hip_bf16.h>
#include <type_traits>

#define NN 50000     // nodes per side (users == items == 50000)
#define NE 600000    // edges per relation
#define HF 256       // hidden features

typedef float f32x4 __attribute__((ext_vector_type(4)));
typedef _Float16 f16x8 __attribute__((ext_vector_type(8)));
typedef _Float16 f16x4 __attribute__((ext_vector_type(4)));

// ---------- fp32 -> fp16 convert, both inputs in one dispatch ----------
__global__ __launch_bounds__(256) void k_tofp16_2(const float* __restrict__ A,
                                                  const float* __restrict__ B,
                                                  _Float16* __restrict__ OA,
                                                  _Float16* __restrict__ OB, int n4) {
  int i = blockIdx.x * 256 + threadIdx.x;
  const float* X = (i < n4) ? A : B;
  _Float16* Y = (i < n4) ? OA : OB;
  int j = (i < n4) ? i : i - n4;
  if (j < n4) {
    float4 v = reinterpret_cast<const float4*>(X)[j];
    f16x4 o = {(_Float16)v.x, (_Float16)v.y, (_Float16)v.z, (_Float16)v.w};
    reinterpret_cast<f16x4*>(Y)[j] = o;
  }
}

// ---------- all 8 W[K][256] -> Wt[256][K] transposes in one dispatch ----------
struct TArgs {
  const float* W[8];
  _Float16* dst[8];
  int K[8];
  int cum[9];
};
__global__ __launch_bounds__(256) void k_transpose_all(TArgs t) {
  int idx = blockIdx.x * 256 + threadIdx.x;
#pragma unroll
  for (int s = 0; s < 8; ++s) {
    if (idx >= t.cum[s] && idx < t.cum[s + 1]) {
      int local = idx - t.cum[s];
      int K = t.K[s];
      int k = local >> 8;
      int n = local & 255;
      t.dst[s][(size_t)n * K + k] = (_Float16)t.W[s][local];
    }
  }
}

// ---------- attn er-projections: out[c][k][h] = sum_d W[c][k, h*64+d] * ar[c][h*64+d] ----------
__global__ __launch_bounds__(256) void k_makeattn2(const float* __restrict__ Wfull,  // [2,K,256]
                                                   const float* __restrict__ ar,    // [2,256]
                                                   int K, float* __restrict__ out) {
  int idx = blockIdx.x * 256 + threadIdx.x;
  if (idx >= 2 * K * 4) return;
  int h = idx & 3;
  int k = (idx >> 2) % K;
  int c = idx / (4 * K);
  const float* W = Wfull + (size_t)c * K * 256;
  const float* a = ar + c * 256 + h * 64;
  const float* wrow = W + (size_t)k * 256 + h * 64;
  float s = 0.f;
#pragma unroll 8
  for (int d = 0; d < 64; ++d) s += wrow[d] * a[d];
  out[(size_t)c * K * 4 + k * 4 + h] = s;
}

// ---------- er GEMV, both relations in one dispatch; one wave per row ----------
__global__ __launch_bounds__(256) void k_gemv_er2(const _Float16* __restrict__ Xi,
                                                  const _Float16* __restrict__ Xu,
                                                  const float* __restrict__ war0,
                                                  const float* __restrict__ war1,
                                                  float* __restrict__ ER0, float* __restrict__ ER1,
                                                  int K) {
  int nb = (NN + 3) / 4;
  int rel = blockIdx.x >= nb;
  int bid = rel ? blockIdx.x - nb : blockIdx.x;
  const _Float16* X = rel ? Xu : Xi;
  const float* wa = rel ? war1 : war0;
  float* out = rel ? ER1 : ER0;
  int wid = bid * 4 + (threadIdx.x >> 6);
  if (wid >= NN) return;
  int lane = threadIdx.x & 63;
  float p0 = 0.f, p1 = 0.f, p2 = 0.f, p3 = 0.f;
  int k0 = lane * 4;
  if (k0 < K) {
    f16x4 x = *reinterpret_cast<const f16x4*>(X + (size_t)wid * K + k0);
    float xv[4] = {(float)x.x, (float)x.y, (float)x.z, (float)x.w};
#pragma unroll
    for (int j = 0; j < 4; ++j) {
      float4 wv = *reinterpret_cast<const float4*>(wa + (k0 + j) * 4);
      p0 += xv[j] * wv.x; p1 += xv[j] * wv.y; p2 += xv[j] * wv.z; p3 += xv[j] * wv.w;
    }
  }
#pragma unroll
  for (int off = 32; off > 0; off >>= 1) {
    p0 += __shfl_down(p0, off); p1 += __shfl_down(p1, off);
    p2 += __shfl_down(p2, off); p3 += __shfl_down(p3, off);
  }
  if (lane == 0)
    *reinterpret_cast<float4*>(out + (size_t)wid * 4) = (float4){p0, p1, p2, p3};
}

// ---------- GEMM pair: Z[side][M,256](fp16) = A[side] @ W[side]; fused el epilogue ----------
__global__ __launch_bounds__(256) void k_gemm2(
    const _Float16* __restrict__ A0, const _Float16* __restrict__ A1,
    const _Float16* __restrict__ Wt0, const _Float16* __restrict__ Wt1,
    _Float16* __restrict__ Z0, _Float16* __restrict__ Z1,
    const float* __restrict__ al0, const float* __restrict__ al1,
    float* __restrict__ EL0, float* __restrict__ EL1,
    int M, int K) {
  int mgrid = (M + 63) / 64;
  int side = blockIdx.x >= mgrid;
  int bid = side ? blockIdx.x - mgrid : blockIdx.x;
  const _Float16* A = side ? A1 : A0;
  const _Float16* Wt = side ? Wt1 : Wt0;
  _Float16* Z = side ? Z1 : Z0;
  const float* al = side ? al1 : al0;
  float* EL = side ? EL1 : EL0;

  int wave = threadIdx.x >> 6;
  int lane = threadIdx.x & 63;
  int lr = lane & 15;   // fragment row (A) / col (B)
  int kg = lane >> 4;   // k-group: k = kg*8 + j
  int row0 = bid * 64;
  int col0 = wave * 64;
  f32x4 acc[4][4];
#pragma unroll
  for (int i = 0; i < 4; ++i)
#pragma unroll
    for (int j = 0; j < 4; ++j) acc[i][j] = (f32x4){0.f, 0.f, 0.f, 0.f};

  for (int k0 = 0; k0 < K; k0 += 32) {
    f16x8 af[4], bfr[4];
#pragma unroll
    for (int mt = 0; mt < 4; ++mt) {
      int r = row0 + mt * 16 + lr;
      if (r >= M) r = M - 1;  // clamp loads; stores are guarded
      af[mt] = *reinterpret_cast<const f16x8*>(A + (size_t)r * K + k0 + kg * 8);
    }
#pragma unroll
    for (int ct = 0; ct < 4; ++ct) {
      int c = col0 + ct * 16 + lr;
      bfr[ct] = *reinterpret_cast<const f16x8*>(Wt + (size_t)c * K + k0 + kg * 8);
    }
#pragma unroll
    for (int mt = 0; mt < 4; ++mt)
#pragma unroll
      for (int ct = 0; ct < 4; ++ct)
        acc[mt][ct] = __builtin_amdgcn_mfma_f32_16x16x32_f16(af[mt], bfr[ct], acc[mt][ct], 0, 0, 0);
  }
  // C/D layout: col = lane&15, row = (lane>>4)*4 + reg
#pragma unroll
  for (int mt = 0; mt < 4; ++mt) {
#pragma unroll
    for (int r = 0; r < 4; ++r) {
      int row = row0 + mt * 16 + kg * 4 + r;
      if (row < M) {
#pragma unroll
        for (int ct = 0; ct < 4; ++ct) {
          int col = col0 + ct * 16 + lr;
          Z[(size_t)row * HF + col] = (_Float16)acc[mt][ct][r];
        }
      }
    }
  }
  // fused el epilogue: el[row][h=wave] = sum_col z[row][col] * al[col]
  float al4[4];
#pragma unroll
  for (int ct = 0; ct < 4; ++ct) al4[ct] = al[wave * 64 + ct * 16 + lr];
#pragma unroll
  for (int mt = 0; mt < 4; ++mt) {
#pragma unroll
    for (int r = 0; r < 4; ++r) {
      float p = acc[mt][0][r] * al4[0] + acc[mt][1][r] * al4[1] +
                acc[mt][2][r] * al4[2] + acc[mt][3][r] * al4[3];
#pragma unroll
      for (int off = 1; off < 16; off <<= 1) p += __shfl_xor(p, off);
      int row = row0 + mt * 16 + kg * 4 + r;
      if (lr == 0 && row < M) EL[(size_t)row * 4 + wave] = p;
    }
  }
}

// ---------- CSR build (both relations per dispatch) ----------
__global__ __launch_bounds__(256) void k_hist2(const int* __restrict__ d0, const int* __restrict__ d1,
                                               int* __restrict__ c0, int* __restrict__ c1) {
  int t = blockIdx.x * 256 + threadIdx.x;
  if (t < NE) atomicAdd(&c0[d0[t]], 1);
  else if (t < 2 * NE) atomicAdd(&c1[d1[t - NE]], 1);
}

__global__ __launch_bounds__(1024) void k_scan1_2(const int* __restrict__ c0, const int* __restrict__ c1,
                                                  int* __restrict__ rp0, int* __restrict__ rp1,
                                                  int* __restrict__ b0, int* __restrict__ b1, int nscan) {
  __shared__ int tmp[1024];
  int rel = blockIdx.x >= nscan;
  int blk = rel ? blockIdx.x - nscan : blockIdx.x;
  const int* counts = rel ? c1 : c0;
  int* rp = rel ? rp1 : rp0;
  int* bsum = rel ? b1 : b0;
  int i = blk * 1024 + threadIdx.x;
  int v = (i < NN) ? counts[i] : 0;
  tmp[threadIdx.x] = v;
  __syncthreads();
  for (int off = 1; off < 1024; off <<= 1) {
    int t = (threadIdx.x >= off) ? tmp[threadIdx.x - off] : 0;
    __syncthreads();
    tmp[threadIdx.x] += t;
    __syncthreads();
  }
  if (i < NN) rp[i] = tmp[threadIdx.x] - v;  // block-local exclusive
  if (threadIdx.x == 1023) bsum[blk] = tmp[1023];
}

__global__ __launch_bounds__(128) void k_scan2_2(int* __restrict__ b0, int* __restrict__ b1, int nb) {
  int rel = threadIdx.x >> 6;
  int l = threadIdx.x & 63;
  int* bsum = rel ? b1 : b0;
  int orig = (l < nb) ? bsum[l] : 0;
  int v = orig;
#pragma unroll
  for (int off = 1; off < 64; off <<= 1) {
    int t = __shfl_up(v, off);
    if (l >= off) v += t;
  }
  if (l < nb) bsum[l] = v - orig;  // exclusive
}

__global__ __launch_bounds__(1024) void k_scan3_2(int* __restrict__ rp0, int* __restrict__ rp1,
                                                  const int* __restrict__ b0, const int* __restrict__ b1,
                                                  int nscan) {
  int rel = blockIdx.x >= nscan;
  int blk = rel ? blockIdx.x - nscan : blockIdx.x;
  int* rp = rel ? rp1 : rp0;
  const int* bsum = rel ? b1 : b0;
  int i = blk * 1024 + threadIdx.x;
  if (i < NN) rp[i] += bsum[blk];
  if (i == 0) rp[NN] = NE;
}

__global__ __launch_bounds__(256) void k_scatter2(
    const int* __restrict__ s0, const int* __restrict__ d0,
    const int* __restrict__ s1, const int* __restrict__ d1,
    const int* __restrict__ rp0, const int* __restrict__ rp1,
    int* __restrict__ f0, int* __restrict__ f1,
    int* __restrict__ cs0, int* __restrict__ cs1) {
  int t = blockIdx.x * 256 + threadIdx.x;
  if (t < NE) {
    int d = d0[t];
    int pos = rp0[d] + atomicAdd(&f0[d], 1);
    cs0[pos] = s0[t];
  } else if (t < 2 * NE) {
    int e = t - NE;
    int d = d1[e];
    int pos = rp1[d] + atomicAdd(&f1[d], 1);
    cs1[pos] = s1[e];
  }
}

__device__ __forceinline__ float pick_h(float4 v, int h) {
  float r = v.x;
  r = (h == 1) ? v.y : r;
  r = (h == 2) ? v.z : r;
  r = (h == 3) ? v.w : r;
  return r;
}

// ---------- fused GAT aggregation, both relations per dispatch ----------
template <typename OT>
__global__ __launch_bounds__(256) void k_agg2(
    const int* __restrict__ rpA, const int* __restrict__ csA,
    const float* __restrict__ elA, const float* __restrict__ erA,
    const _Float16* __restrict__ ZA, const float* __restrict__ bA, OT* __restrict__ oA,
    const int* __restrict__ rpB, const int* __restrict__ csB,
    const float* __restrict__ elB, const float* __restrict__ erB,
    const _Float16* __restrict__ ZB, const float* __restrict__ bB, OT* __restrict__ oB) {
  __shared__ float exs[4][256];
  __shared__ int ssrc[4][64];
  int nb = (NN + 3) / 4;
  int rel = blockIdx.x >= nb;
  int bid = rel ? blockIdx.x - nb : blockIdx.x;
  const int* rp = rel ? rpB : rpA;
  const int* csrc = rel ? csB : csA;
  const float* el = rel ? elB : elA;
  const float* er = rel ? erB : erA;
  const _Float16* Z = rel ? ZB : ZA;
  const float* bias = rel ? bB : bA;
  OT* out = rel ? oB : oA;

  int wv = threadIdx.x >> 6;
  int wid = bid * 4 + wv;
  if (wid >= NN) return;
  int lane = threadIdx.x & 63;
  int half = lane >> 5, l5 = lane & 31;
  int c0 = l5 * 8;      // 8 cols per lane (halves cover full row)
  int h = l5 >> 3;      // head for cols c0..c0+7
  int beg = rp[wid], end = rp[wid + 1];
  int deg = end - beg;

  if (deg == 0) {
    if (half == 0) {
      float4 b0 = *reinterpret_cast<const float4*>(bias + c0);
      float4 b1 = *reinterpret_cast<const float4*>(bias + c0 + 4);
      if constexpr (std::is_same<OT, float>::value) {
        float4* op = reinterpret_cast<float4*>(out + (size_t)wid * HF + c0);
        op[0] = b0; op[1] = b1;
      } else {
        f16x8 o = {(_Float16)b0.x, (_Float16)b0.y, (_Float16)b0.z, (_Float16)b0.w,
                   (_Float16)b1.x, (_Float16)b1.y, (_Float16)b1.z, (_Float16)b1.w};
        *reinterpret_cast<f16x8*>(out + (size_t)wid * HF + c0) = o;
      }
    }
    return;
  }

  if (deg <= 64) {
    // ---- pass A: lane i owns edge i ----
    int s = 0;
    float4 x = {-1e30f, -1e30f, -1e30f, -1e30f};
    float4 b = *reinterpret_cast<const float4*>(er + (size_t)wid * 4);
    if (lane < deg) {
      s = csrc[beg + lane];
      float4 a = reinterpret_cast<const float4*>(el)[s];
      x.x = a.x + b.x; x.x = x.x >= 0.f ? x.x : 0.2f * x.x;
      x.y = a.y + b.y; x.y = x.y >= 0.f ? x.y : 0.2f * x.y;
      x.z = a.z + b.z; x.z = x.z >= 0.f ? x.z : 0.2f * x.z;
      x.w = a.w + b.w; x.w = x.w >= 0.f ? x.w : 0.2f * x.w;
    }
    float4 m = x;
#pragma unroll
    for (int off = 32; off > 0; off >>= 1) {
      m.x = fmaxf(m.x, __shfl_xor(m.x, off));
      m.y = fmaxf(m.y, __shfl_xor(m.y, off));
      m.z = fmaxf(m.z, __shfl_xor(m.z, off));
      m.w = fmaxf(m.w, __shfl_xor(m.w, off));
    }
    float4 ex = {0.f, 0.f, 0.f, 0.f};
    if (lane < deg) {
      ex.x = __expf(x.x - m.x);
      ex.y = __expf(x.y - m.y);
      ex.z = __expf(x.z - m.z);
      ex.w = __expf(x.w - m.w);
    }
    float4 sm = ex;
#pragma unroll
    for (int off = 32; off > 0; off >>= 1) {
      sm.x += __shfl_xor(sm.x, off);
      sm.y += __shfl_xor(sm.y, off);
      sm.z += __shfl_xor(sm.z, off);
      sm.w += __shfl_xor(sm.w, off);
    }
    float inv = 1.0f / pick_h(sm, h);
    if (lane < deg) {
      *reinterpret_cast<float4*>(&exs[wv][lane * 4]) = ex;
      ssrc[wv][lane] = s;
    }
    // ---- pass B: halves own alternate edges, 4-group unroll -> 8 gathers in flight ----
    float a8[8] = {0.f, 0.f, 0.f, 0.f, 0.f, 0.f, 0.f, 0.f};
    int j = half;
#define AGG_STEP(J)                                                        \
    {                                                                      \
      int sj = ssrc[wv][(J)];                                              \
      float wj = exs[wv][(J) * 4 + h];                                     \
      f16x8 z = *reinterpret_cast<const f16x8*>(Z + (size_t)sj * HF + c0); \
      _Pragma("unroll")                                                    \
      for (int q = 0; q < 8; ++q) a8[q] += wj * (float)z[q];               \
    }
    for (; j + 6 < deg; j += 8) {
      AGG_STEP(j); AGG_STEP(j + 2); AGG_STEP(j + 4); AGG_STEP(j + 6);
    }
    for (; j < deg; j += 2) { AGG_STEP(j); }
#undef AGG_STEP
#pragma unroll
    for (int q = 0; q < 8; ++q) a8[q] += __shfl_xor(a8[q], 32);
    if (half == 0) {
      float4 b0 = *reinterpret_cast<const float4*>(bias + c0);
      float4 b1 = *reinterpret_cast<const float4*>(bias + c0 + 4);
      float r0 = a8[0] * inv + b0.x, r1 = a8[1] * inv + b0.y;
      float r2 = a8[2] * inv + b0.z, r3 = a8[3] * inv + b0.w;
      float r4 = a8[4] * inv + b1.x, r5 = a8[5] * inv + b1.y;
      float r6 = a8[6] * inv + b1.z, r7 = a8[7] * inv + b1.w;
      if constexpr (std::is_same<OT, float>::value) {
        float4* op = reinterpret_cast<float4*>(out + (size_t)wid * HF + c0);
        op[0] = (float4){r0, r1, r2, r3};
        op[1] = (float4){r4, r5, r6, r7};
      } else {
        f16x8 o = {(_Float16)r0, (_Float16)r1, (_Float16)r2, (_Float16)r3,
                   (_Float16)r4, (_Float16)r5, (_Float16)r6, (_Float16)r7};
        *reinterpret_cast<f16x8*>(out + (size_t)wid * HF + c0) = o;
      }
    }
    return;
  }

  // ---- rare fallback (deg > 64): uniform two-pass, full-wave f16x4 mapping ----
  {
    int c4 = lane * 4;
    int h4 = lane >> 4;
    float4 b = *reinterpret_cast<const float4*>(er + (size_t)wid * 4);
    float4 m = {-1e30f, -1e30f, -1e30f, -1e30f};
    for (int e = beg; e < end; ++e) {
      int s = csrc[e];
      float4 a = reinterpret_cast<const float4*>(el)[s];
      float4 x;
      x.x = a.x + b.x; x.x = x.x >= 0.f ? x.x : 0.2f * x.x;
      x.y = a.y + b.y; x.y = x.y >= 0.f ? x.y : 0.2f * x.y;
      x.z = a.z + b.z; x.z = x.z >= 0.f ? x.z : 0.2f * x.z;
      x.w = a.w + b.w; x.w = x.w >= 0.f ? x.w : 0.2f * x.w;
      m.x = fmaxf(m.x, x.x); m.y = fmaxf(m.y, x.y);
      m.z = fmaxf(m.z, x.z); m.w = fmaxf(m.w, x.w);
    }
    float4 sm = {0.f, 0.f, 0.f, 0.f};
    float4 acc = {0.f, 0.f, 0.f, 0.f};
    for (int e = beg; e < end; ++e) {
      int s = csrc[e];
      float4 a = reinterpret_cast<const float4*>(el)[s];
      float4 x;
      x.x = a.x + b.x; x.x = x.x >= 0.f ? x.x : 0.2f * x.x;
      x.y = a.y + b.y; x.y = x.y >= 0.f ? x.y : 0.2f * x.y;
      x.z = a.z + b.z; x.z = x.z >= 0.f ? x.z : 0.2f * x.z;
      x.w = a.w + b.w; x.w = x.w >= 0.f ? x.w : 0.2f * x.w;
      float4 exv;
      exv.x = __expf(x.x - m.x); exv.y = __expf(x.y - m.y);
      exv.z = __expf(x.z - m.z); exv.w = __expf(x.w - m.w);
      sm.x += exv.x; sm.y += exv.y; sm.z += exv.z; sm.w += exv.w;
      float w0 = pick_h(exv, h4);
      f16x4 z0 = *reinterpret_cast<const f16x4*>(Z + (size_t)s * HF + c4);
      acc.x += w0 * (float)z0.x;
      acc.y += w0 * (float)z0.y;
      acc.z += w0 * (float)z0.z;
      acc.w += w0 * (float)z0.w;
    }
    float inv = 1.0f / pick_h(sm, h4);
    float4 bv = *reinterpret_cast<const float4*>(bias + c4);
    float r0 = acc.x * inv + bv.x, r1 = acc.y * inv + bv.y;
    float r2 = acc.z * inv + bv.z, r3 = acc.w * inv + bv.w;
    if constexpr (std::is_same<OT, float>::value) {
      *reinterpret_cast<float4*>(out + (size_t)wid * HF + c4) = (float4){r0, r1, r2, r3};
    } else {
      f16x4 o = {(_Float16)r0, (_Float16)r1, (_Float16)r2, (_Float16)r3};
      *reinterpret_cast<f16x4*>(out + (size_t)wid * HF + c4) = o;
    }
  }
}

// ---------- batchnorm, both sides per dispatch ----------
__global__ __launch_bounds__(256) void k_bn_stats2(const _Float16* __restrict__ XU,
                                                   const _Float16* __restrict__ XI,
                                                   float* __restrict__ su, float* __restrict__ qu,
                                                   float* __restrict__ si, float* __restrict__ qi) {
  int rel = blockIdx.x >> 9;  // grid = 1024
  int blk = blockIdx.x & 511;
  const _Float16* X = rel ? XI : XU;
  float* sums = rel ? si : su;
  float* sqs = rel ? qi : qu;
  int c = threadIdx.x;
  float s = 0.f, q = 0.f;
  for (int r = blk; r < NN; r += 512) {
    float v = (float)X[(size_t)r * HF + c];
    s += v;
    q += v * v;
  }
  atomicAdd(&sums[c], s);
  atomicAdd(&sqs[c], q);
}

__global__ __launch_bounds__(256) void k_bn_apply2(
    const _Float16* __restrict__ XU, const _Float16* __restrict__ XI,
    const float* __restrict__ su, const float* __restrict__ qu,
    const float* __restrict__ si, const float* __restrict__ qi,
    const float* __restrict__ gU, const float* __restrict__ btU,
    const float* __restrict__ gI, const float* __restrict__ btI,
    _Float16* __restrict__ YU, _Float16* __restrict__ YI, int act) {
  const int nb = NN * HF / 8 / 256;  // 6250
  int rel = blockIdx.x >= nb;
  int bid = rel ? blockIdx.x - nb : blockIdx.x;
  const _Float16* X = rel ? XI : XU;
  const float* sums = rel ? si : su;
  const float* sqs = rel ? qi : qu;
  const float* g = rel ? gI : gU;
  const float* bt = rel ? btI : btU;
  _Float16* Y = rel ? YI : YU;
  int gid = bid * 256 + threadIdx.x;
  int i0 = gid * 8;
  int c0 = i0 & 255;
  const float invN = 1.0f / NN;
  f16x8 xv = *reinterpret_cast<const f16x8*>(X + i0);
  float4 s0 = *reinterpret_cast<const float4*>(sums + c0);
  float4 s1 = *reinterpret_cast<const float4*>(sums + c0 + 4);
  float4 q0 = *reinterpret_cast<const float4*>(sqs + c0);
  float4 q1 = *reinterpret_cast<const float4*>(sqs + c0 + 4);
  float4 g0 = *reinterpret_cast<const float4*>(g + c0);
  float4 g1 = *reinterpret_cast<const float4*>(g + c0 + 4);
  float4 b0 = *reinterpret_cast<const float4*>(bt + c0);
  float4 b1 = *reinterpret_cast<const float4*>(bt + c0 + 4);
  float sa[8] = {s0.x, s0.y, s0.z, s0.w, s1.x, s1.y, s1.z, s1.w};
  float qa[8] = {q0.x, q0.y, q0.z, q0.w, q1.x, q1.y, q1.z, q1.w};
  float ga[8] = {g0.x, g0.y, g0.z, g0.w, g1.x, g1.y, g1.z, g1.w};
  float ba[8] = {b0.x, b0.y, b0.z, b0.w, b1.x, b1.y, b1.z, b1.w};
  f16x8 o;
#pragma unroll
  for (int j = 0; j < 8; ++j) {
    float mu = sa[j] * invN;
    float var = qa[j] * invN - mu * mu;
    float sc = rsqrtf(var + 1e-5f) * ga[j];
    float v = ((float)xv[j] - mu) * sc + ba[j];
    v = act ? tanhf(v) : (v >= 0.f ? v : 0.01f * v);
    o[j] = (_Float16)v;
  }
  *reinterpret_cast<f16x8*>(Y + i0) = o;
}

extern "C" void kernel_launch(void* const* d_in, const int* in_sizes, int n_in,
                              void* d_out, int out_size, void* d_ws, size_t ws_size,
                              hipStream_t stream) {
  (void)in_sizes; (void)n_in; (void)out_size; (void)ws_size;
  const float* x_user = (const float*)d_in[0];
  const float* x_item = (const float*)d_in[1];
  const int* ui_src = (const int*)d_in[2];
  const int* ui_dst = (const int*)d_in[3];
  const int* iu_src = (const int*)d_in[4];
  const int* iu_dst = (const int*)d_in[5];
  const float *Wp[4], *alp[4], *arp[4], *bp[4];
  for (int l = 0; l < 4; ++l) {
    Wp[l]  = (const float*)d_in[6 + 4 * l];
    alp[l] = (const float*)d_in[7 + 4 * l];
    arp[l] = (const float*)d_in[8 + 4 * l];
    bp[l]  = (const float*)d_in[9 + 4 * l];
  }
  const float* bng = (const float*)d_in[22];
  const float* bnb = (const float*)d_in[23];

  char* w = (char*)d_ws;
  auto alloc = [&](size_t bytes) -> void* {
    void* p = (void*)w;
    w += (bytes + 255) & ~(size_t)255;
    return p;
  };
  _Float16* XU16 = (_Float16*)alloc((size_t)NN * 128 * 2);
  _Float16* XI16 = (_Float16*)alloc((size_t)NN * 128 * 2);
  _Float16* H16U = (_Float16*)alloc((size_t)NN * HF * 2);
  _Float16* H16I = (_Float16*)alloc((size_t)NN * HF * 2);
  _Float16* Z0 = (_Float16*)alloc((size_t)NN * HF * 2);
  _Float16* Z1 = (_Float16*)alloc((size_t)NN * HF * 2);
  _Float16* RAW16U = (_Float16*)alloc((size_t)NN * HF * 2);
  _Float16* RAW16I = (_Float16*)alloc((size_t)NN * HF * 2);
  float* EL0 = (float*)alloc((size_t)NN * 4 * 4);
  float* ER0 = (float*)alloc((size_t)NN * 4 * 4);
  float* EL1 = (float*)alloc((size_t)NN * 4 * 4);
  float* ER1 = (float*)alloc((size_t)NN * 4 * 4);
  _Float16* WT = (_Float16*)alloc((size_t)8 * 65536 * 2);
  float* ATTN = (float*)alloc((size_t)2 * 256 * 4 * 4);
  int* rp_ui = (int*)alloc((size_t)(NN + 1) * 4);
  int* rp_iu = (int*)alloc((size_t)(NN + 1) * 4);
  int* csrc_ui = (int*)alloc((size_t)NE * 4);
  int* csrc_iu = (int*)alloc((size_t)NE * 4);
  int* counts = (int*)alloc((size_t)4 * NN * 4);  // counts_ui | counts_iu | fill_ui | fill_iu
  int* bsum_ui = (int*)alloc((size_t)64 * 4);
  int* bsum_iu = (int*)alloc((size_t)64 * 4);
  float* stats = (float*)alloc((size_t)6 * 512 * 4);

  int* counts_ui = counts;
  int* counts_iu = counts + NN;
  int* fill_ui = counts + 2 * NN;
  int* fill_iu = counts + 3 * NN;

  hipMemsetAsync(counts, 0, (size_t)4 * NN * 4, stream);
  hipMemsetAsync(stats, 0, (size_t)6 * 512 * 4, stream);

  // input conversion (one dispatch)
  int n4 = NN * 128 / 4;
  k_tofp16_2<<<(2 * n4 + 255) / 256, 256, 0, stream>>>(x_user, x_item, XU16, XI16, n4);

  // all weight transposes (one dispatch)
  TArgs ta;
  int cum = 0;
  for (int l = 0; l < 4; ++l) {
    int K = (l == 0) ? 128 : 256;
    for (int r = 0; r < 2; ++r) {
      int s = l * 2 + r;
      ta.W[s] = Wp[l] + (size_t)r * K * HF;
      ta.dst[s] = WT + (size_t)s * 65536;
      ta.K[s] = K;
      ta.cum[s] = cum;
      cum += K * 256;
    }
  }
  ta.cum[8] = cum;
  k_transpose_all<<<(cum + 255) / 256, 256, 0, stream>>>(ta);

  // CSR build (both relations per dispatch)
  int egrid2 = (2 * NE + 255) / 256;
  int nscan = (NN + 1023) / 1024;
  k_hist2<<<egrid2, 256, 0, stream>>>(ui_dst, iu_dst, counts_ui, counts_iu);
  k_scan1_2<<<2 * nscan, 1024, 0, stream>>>(counts_ui, counts_iu, rp_ui, rp_iu, bsum_ui, bsum_iu, nscan);
  k_scan2_2<<<1, 128, 0, stream>>>(bsum_ui, bsum_iu, nscan);
  k_scan3_2<<<2 * nscan, 1024, 0, stream>>>(rp_ui, rp_iu, bsum_ui, bsum_iu, nscan);
  k_scatter2<<<egrid2, 256, 0, stream>>>(ui_src, ui_dst, iu_src, iu_dst, rp_ui, rp_iu,
                                         fill_ui, fill_iu, csrc_ui, csrc_iu);

  const _Float16* hu16 = XU16;
  const _Float16* hi16 = XI16;
  int agrid = (NN + 3) / 4;
  float* out_user = (float*)d_out;
  float* out_item = (float*)d_out + (size_t)NN * HF;

  for (int l = 0; l < 4; ++l) {
    int K = (l == 0) ? 128 : 256;
    const _Float16* W0t = WT + (size_t)(l * 2 + 0) * 65536;
    const _Float16* W1t = WT + (size_t)(l * 2 + 1) * 65536;
    int mgrid = (NN + 63) / 64;

    // er projection tables: war0 | war1, each [K][4]
    k_makeattn2<<<(2 * K * 4 + 255) / 256, 256, 0, stream>>>(Wp[l], arp[l], K, ATTN);
    // er0 = hi @ (W0.ar0), er1 = hu @ (W1.ar1)   (one dispatch)
    k_gemv_er2<<<2 * agrid, 256, 0, stream>>>(hi16, hu16, ATTN, ATTN + (size_t)K * 4, ER0, ER1, K);

    // GEMM pair: Z0 = hu@W0 (+el0), Z1 = hi@W1 (+el1)
    k_gemm2<<<2 * mgrid, 256, 0, stream>>>(hu16, hi16, W0t, W1t, Z0, Z1,
                                           alp[l] + 0, alp[l] + 256, EL0, EL1, NN, K);

    // aggregation pair: u->i (dst items, Z0) and i->u (dst users, Z1)
    if (l < 3)
      k_agg2<_Float16><<<2 * agrid, 256, 0, stream>>>(
          rp_ui, csrc_ui, EL0, ER0, Z0, bp[l] + 0, RAW16I,
          rp_iu, csrc_iu, EL1, ER1, Z1, bp[l] + 256, RAW16U);
    else
      k_agg2<float><<<2 * agrid, 256, 0, stream>>>(
          rp_ui, csrc_ui, EL0, ER0, Z0, bp[l] + 0, out_item,
          rp_iu, csrc_iu, EL1, ER1, Z1, bp[l] + 256, out_user);

    if (l < 3) {
      int act = (l == 2) ? 1 : 0;
      float* su = stats + (size_t)(l * 2 + 0) * 512;
      float* qu = su + 256;
      float* si = stats + (size_t)(l * 2 + 1) * 512;
      float* qi = si + 256;
      k_bn_stats2<<<1024, 256, 0, stream>>>(RAW16U, RAW16I, su, qu, si, qi);
      k_bn_apply2<<<2 * (NN * HF / 8 / 256), 256, 0, stream>>>(
          RAW16U, RAW16I, su, qu, si, qi,
          bng + (size_t)(l * 2 + 0) * 256, bnb + (size_t)(l * 2 + 0) * 256,
          bng + (size_t)(l * 2 + 1) * 256, bnb + (size_t)(l * 2 + 1) * 256,
          H16U, H16I, act);
      hu16 = H16U;
      hi16 = H16I;
    }
  }
}